// Round 1
// baseline (593.995 us; speedup 1.0000x reference)
//
#include <hip/hip_runtime.h>

#define N_NODES 100000
#define N_EDGES 1000000
#define F_IN 128
#define F_HID 256
#define F_OUT 40

// ---------------- CSR build ----------------

__global__ void k_init(int* __restrict__ cnt, int* __restrict__ cursor) {
    int i = blockIdx.x * 256 + threadIdx.x;
    if (i < N_NODES) { cnt[i] = 0; cursor[i] = 0; }
}

__global__ void k_count(const int* __restrict__ dst, int* __restrict__ cnt) {
    int e = blockIdx.x * 256 + threadIdx.x;
    if (e < N_EDGES) atomicAdd(&cnt[dst[e]], 1);
}

// 98 blocks x 256 threads, 4 items/thread: per-block exclusive scan + dinv
__global__ void k_scan_partial(const int* __restrict__ cnt, int* __restrict__ rowstart,
                               float* __restrict__ dinv, int* __restrict__ bsum) {
    __shared__ int wsum[4];
    int tid = threadIdx.x;
    int base = blockIdx.x * 1024 + tid * 4;
    int v[4];
#pragma unroll
    for (int j = 0; j < 4; j++) {
        int i = base + j;
        v[j] = (i < N_NODES) ? cnt[i] : 0;
        if (i < N_NODES) dinv[i] = rsqrtf((float)v[j] + 1.0f);  // +1 self-loop
    }
    int t = v[0] + v[1] + v[2] + v[3];
    int lane = tid & 63, wave = tid >> 6;
    int incl = t;
#pragma unroll
    for (int off = 1; off < 64; off <<= 1) {
        int u = __shfl_up(incl, off);
        if (lane >= off) incl += u;
    }
    if (lane == 63) wsum[wave] = incl;
    __syncthreads();
    int woff = 0;
    for (int w = 0; w < wave; w++) woff += wsum[w];
    int run = woff + incl - t;  // exclusive prefix for this thread's first item
#pragma unroll
    for (int j = 0; j < 4; j++) {
        int i = base + j;
        if (i < N_NODES) rowstart[i] = run;
        run += v[j];
    }
    if (tid == 255) bsum[blockIdx.x] = woff + incl;  // block total
}

// single block, 128 threads: scan the (<=128) block sums
__global__ void k_scan_blocks(const int* __restrict__ bsum, int* __restrict__ boff,
                              int* __restrict__ rowstart, int nb) {
    __shared__ int wtot[2];
    int tid = threadIdx.x;
    int v = (tid < nb) ? bsum[tid] : 0;
    int lane = tid & 63, wave = tid >> 6;
    int incl = v;
#pragma unroll
    for (int off = 1; off < 64; off <<= 1) {
        int u = __shfl_up(incl, off);
        if (lane >= off) incl += u;
    }
    if (lane == 63) wtot[wave] = incl;
    __syncthreads();
    int excl = incl - v + (wave ? wtot[0] : 0);
    if (tid < nb) boff[tid] = excl;
    if (tid == 0) rowstart[N_NODES] = N_EDGES;  // total count is exactly E
}

__global__ void k_add_off(int* __restrict__ rowstart, const int* __restrict__ boff) {
    int base = blockIdx.x * 1024 + threadIdx.x * 4;
    int off = boff[blockIdx.x];
#pragma unroll
    for (int j = 0; j < 4; j++) {
        int i = base + j;
        if (i < N_NODES) rowstart[i] += off;
    }
}

__global__ void k_fill(const int* __restrict__ src, const int* __restrict__ dst,
                       const int* __restrict__ rowstart, int* __restrict__ cursor,
                       int* __restrict__ esrc) {
    int e = blockIdx.x * 256 + threadIdx.x;
    if (e < N_EDGES) {
        int d = dst[e];
        int p = rowstart[d] + atomicAdd(&cursor[d], 1);
        esrc[p] = src[e];
    }
}

// ---------------- layer 1 aggregation (on raw x, 128 feat) ----------------
// one wave per node; lane holds float2 (128 feats / 64 lanes)
__global__ void k_agg1(const float* __restrict__ x, const float* __restrict__ dinv,
                       const int* __restrict__ rowstart, const int* __restrict__ esrc,
                       float* __restrict__ xagg) {
    int node = blockIdx.x * 4 + (threadIdx.x >> 6);
    int lane = threadIdx.x & 63;
    const float2* x2 = (const float2*)x;
    float di = dinv[node];
    float2 v = x2[node * 64 + lane];
    float ax = di * v.x, ay = di * v.y;  // self-loop term (one di now, one at end)
    int e0 = rowstart[node], e1 = rowstart[node + 1];
    for (int e = e0; e < e1; ++e) {
        int s = esrc[e];
        float w = dinv[s];
        float2 u = x2[s * 64 + lane];
        ax += w * u.x;
        ay += w * u.y;
    }
    float2 o;
    o.x = ax * di;
    o.y = ay * di;
    ((float2*)xagg)[node * 64 + lane] = o;
}

// ---------------- GEMM1: h = relu(xagg @ W1 + b1)  [1e5,128]x[128,256] ----------------
// tile 128x128, K-chunks of 32, 8x8 micro-tile per thread
__launch_bounds__(256)
__global__ void k_gemm1(const float* __restrict__ A, const float* __restrict__ W,
                        const float* __restrict__ bias, float* __restrict__ C) {
    __shared__ float a_s[32][132];  // [k][m], padded (132*4B = 16B-aligned rows)
    __shared__ float b_s[32][132];  // [k][n]
    int tid = threadIdx.x;
    int row0 = blockIdx.x * 128;
    int col0 = blockIdx.y * 128;
    int tx = tid & 15, ty = tid >> 4;
    float acc[8][8];
#pragma unroll
    for (int i = 0; i < 8; i++)
#pragma unroll
        for (int j = 0; j < 8; j++) acc[i][j] = 0.0f;

    for (int kc = 0; kc < 4; ++kc) {
        int k0 = kc * 32;
        // A tile: 128 rows x 32 k  (transposed store)
#pragma unroll
        for (int i = 0; i < 4; i++) {
            int f = tid + i * 256;
            int r = f >> 3, c4 = f & 7;
            int row = row0 + r;
            float4 v = make_float4(0.f, 0.f, 0.f, 0.f);
            if (row < N_NODES) v = *(const float4*)(A + row * F_IN + k0 + c4 * 4);
            a_s[c4 * 4 + 0][r] = v.x;
            a_s[c4 * 4 + 1][r] = v.y;
            a_s[c4 * 4 + 2][r] = v.z;
            a_s[c4 * 4 + 3][r] = v.w;
        }
        // B tile: 32 k x 128 n
#pragma unroll
        for (int i = 0; i < 4; i++) {
            int f = tid + i * 256;
            int k = f >> 5, c4 = f & 31;
            float4 v = *(const float4*)(W + (k0 + k) * F_HID + col0 + c4 * 4);
            *(float4*)&b_s[k][c4 * 4] = v;
        }
        __syncthreads();
#pragma unroll
        for (int k = 0; k < 32; k++) {
            float a8[8], b8[8];
            *(float4*)&a8[0] = *(const float4*)&a_s[k][ty * 8];
            *(float4*)&a8[4] = *(const float4*)&a_s[k][ty * 8 + 4];
            *(float4*)&b8[0] = *(const float4*)&b_s[k][tx * 8];
            *(float4*)&b8[4] = *(const float4*)&b_s[k][tx * 8 + 4];
#pragma unroll
            for (int i = 0; i < 8; i++)
#pragma unroll
                for (int j = 0; j < 8; j++) acc[i][j] += a8[i] * b8[j];
        }
        __syncthreads();
    }
    float bias8[8];
    *(float4*)&bias8[0] = *(const float4*)(bias + col0 + tx * 8);
    *(float4*)&bias8[4] = *(const float4*)(bias + col0 + tx * 8 + 4);
#pragma unroll
    for (int i = 0; i < 8; i++) {
        int row = row0 + ty * 8 + i;
        if (row < N_NODES) {
            float o[8];
#pragma unroll
            for (int j = 0; j < 8; j++) o[j] = fmaxf(acc[i][j] + bias8[j], 0.0f);
            *(float4*)(C + row * F_HID + col0 + tx * 8) = *(float4*)&o[0];
            *(float4*)(C + row * F_HID + col0 + tx * 8 + 4) = *(float4*)&o[4];
        }
    }
}

// ---------------- GEMM2: h2 = h @ W2  [1e5,256]x[256,40] (cols padded to 64) ----------------
// tile 128 x 64(pad), K-chunks of 64, 8x4 micro-tile
__launch_bounds__(256)
__global__ void k_gemm2(const float* __restrict__ A, const float* __restrict__ W,
                        float* __restrict__ C) {
    __shared__ float a_s[64][132];  // [k][m]
    __shared__ float b_s[64][68];   // [k][n] (n 0..39 real, 40..63 zero)
    int tid = threadIdx.x;
    int row0 = blockIdx.x * 128;
    int tx = tid & 15, ty = tid >> 4;
    float acc[8][4];
#pragma unroll
    for (int i = 0; i < 8; i++)
#pragma unroll
        for (int j = 0; j < 4; j++) acc[i][j] = 0.0f;

    for (int kc = 0; kc < 4; ++kc) {
        int k0 = kc * 64;
#pragma unroll
        for (int i = 0; i < 8; i++) {
            int f = tid + i * 256;
            int r = f >> 4, c4 = f & 15;
            int row = row0 + r;
            float4 v = make_float4(0.f, 0.f, 0.f, 0.f);
            if (row < N_NODES) v = *(const float4*)(A + row * F_HID + k0 + c4 * 4);
            a_s[c4 * 4 + 0][r] = v.x;
            a_s[c4 * 4 + 1][r] = v.y;
            a_s[c4 * 4 + 2][r] = v.z;
            a_s[c4 * 4 + 3][r] = v.w;
        }
#pragma unroll
        for (int i = 0; i < 4; i++) {
            int f = tid + i * 256;
            int k = f >> 4, c4 = f & 15;
            float4 v = make_float4(0.f, 0.f, 0.f, 0.f);
            if (c4 < 10) v = *(const float4*)(W + (k0 + k) * F_OUT + c4 * 4);
            *(float4*)&b_s[k][c4 * 4] = v;
        }
        __syncthreads();
#pragma unroll
        for (int k = 0; k < 64; k++) {
            float a8[8], b4[4];
            *(float4*)&a8[0] = *(const float4*)&a_s[k][ty * 8];
            *(float4*)&a8[4] = *(const float4*)&a_s[k][ty * 8 + 4];
            *(float4*)&b4[0] = *(const float4*)&b_s[k][tx * 4];
#pragma unroll
            for (int i = 0; i < 8; i++)
#pragma unroll
                for (int j = 0; j < 4; j++) acc[i][j] += a8[i] * b4[j];
        }
        __syncthreads();
    }
    if (tx < 10) {  // only real cols 0..39
#pragma unroll
        for (int i = 0; i < 8; i++) {
            int row = row0 + ty * 8 + i;
            if (row < N_NODES) {
                float4 o = make_float4(acc[i][0], acc[i][1], acc[i][2], acc[i][3]);
                *(float4*)(C + row * F_OUT + tx * 4) = o;
            }
        }
    }
}

// ---------------- layer 2 aggregation + bias + log_softmax ----------------
// one wave per node; lanes 0..39 hold the 40 output features
__global__ void k_agg2(const float* __restrict__ h2, const float* __restrict__ dinv,
                       const int* __restrict__ rowstart, const int* __restrict__ esrc,
                       const float* __restrict__ b2, float* __restrict__ out) {
    int node = blockIdx.x * 4 + (threadIdx.x >> 6);
    int lane = threadIdx.x & 63;
    float di = dinv[node];
    bool act = lane < F_OUT;
    float acc = 0.0f;
    if (act) acc = di * h2[node * F_OUT + lane];  // self-loop
    int e0 = rowstart[node], e1 = rowstart[node + 1];
    for (int e = e0; e < e1; ++e) {
        int s = esrc[e];
        float w = dinv[s];
        if (act) acc += w * h2[s * F_OUT + lane];
    }
    float val = act ? (di * acc + b2[lane]) : -3.0e38f;
    float m = val;
#pragma unroll
    for (int off = 32; off; off >>= 1) m = fmaxf(m, __shfl_xor(m, off));
    float ex = act ? expf(val - m) : 0.0f;
    float ssum = ex;
#pragma unroll
    for (int off = 32; off; off >>= 1) ssum += __shfl_xor(ssum, off);
    if (act) out[node * F_OUT + lane] = val - m - logf(ssum);
}

// ---------------- launch ----------------

extern "C" void kernel_launch(void* const* d_in, const int* in_sizes, int n_in,
                              void* d_out, int out_size, void* d_ws, size_t ws_size,
                              hipStream_t stream) {
    const float* x  = (const float*)d_in[0];
    const int* edge = (const int*)d_in[1];  // int32: jnp int64 is downcast (x64 disabled)
    const float* W1 = (const float*)d_in[2];
    const float* b1 = (const float*)d_in[3];
    const float* W2 = (const float*)d_in[4];
    const float* b2 = (const float*)d_in[5];
    float* out = (float*)d_out;
    const int* src = edge;
    const int* dst = edge + N_EDGES;

    char* ws = (char*)d_ws;
    size_t off = 0;
    auto alloc = [&](size_t bytes) -> void* {
        void* p = ws + off;
        off = (off + bytes + 255) & ~(size_t)255;
        return p;
    };
    float* dinv   = (float*)alloc((size_t)N_NODES * 4);
    int* cnt      = (int*)alloc((size_t)N_NODES * 4);
    int* cursor   = (int*)alloc((size_t)N_NODES * 4);
    int* rowstart = (int*)alloc((size_t)(N_NODES + 1) * 4);
    int* bsum     = (int*)alloc(128 * 4);
    int* boff     = (int*)alloc(128 * 4);
    int* esrc     = (int*)alloc((size_t)N_EDGES * 4);
    float* xagg   = (float*)alloc((size_t)N_NODES * F_IN * 4);   // 51.2 MB
    float* h      = (float*)alloc((size_t)N_NODES * F_HID * 4);  // 102.4 MB
    float* h2     = (float*)alloc((size_t)N_NODES * F_OUT * 4);  // 16 MB
    (void)ws_size; (void)in_sizes; (void)n_in; (void)out_size;

    int nb = (N_NODES + 1023) / 1024;  // 98

    hipLaunchKernelGGL(k_init, dim3((N_NODES + 255) / 256), dim3(256), 0, stream, cnt, cursor);
    hipLaunchKernelGGL(k_count, dim3((N_EDGES + 255) / 256), dim3(256), 0, stream, dst, cnt);
    hipLaunchKernelGGL(k_scan_partial, dim3(nb), dim3(256), 0, stream, cnt, rowstart, dinv, bsum);
    hipLaunchKernelGGL(k_scan_blocks, dim3(1), dim3(128), 0, stream, bsum, boff, rowstart, nb);
    hipLaunchKernelGGL(k_add_off, dim3(nb), dim3(256), 0, stream, rowstart, boff);
    hipLaunchKernelGGL(k_fill, dim3((N_EDGES + 255) / 256), dim3(256), 0, stream, src, dst, rowstart, cursor, esrc);
    hipLaunchKernelGGL(k_agg1, dim3(N_NODES / 4), dim3(256), 0, stream, x, dinv, rowstart, esrc, xagg);
    hipLaunchKernelGGL(k_gemm1, dim3(782, 2), dim3(256), 0, stream, xagg, W1, b1, h);
    hipLaunchKernelGGL(k_gemm2, dim3(782), dim3(256), 0, stream, h, W2, h2);
    hipLaunchKernelGGL(k_agg2, dim3(N_NODES / 4), dim3(256), 0, stream, h2, dinv, rowstart, esrc, b2, out);
}

// Round 2
// 449.746 us; speedup vs baseline: 1.3207x; 1.3207x over previous
//
#include <hip/hip_runtime.h>

#define N_NODES 100000
#define N_EDGES 1000000
#define F_IN 128
#define F_HID 256
#define F_OUT 40

typedef __attribute__((ext_vector_type(8))) short bf16x8;
typedef __attribute__((ext_vector_type(4))) float f32x4;

__device__ inline unsigned short f2bf(float f) {
    unsigned int u = __float_as_uint(f);
    return (unsigned short)((u + 0x7fffu + ((u >> 16) & 1u)) >> 16);
}
__device__ inline float bflo(unsigned int u) { return __uint_as_float(u << 16); }
__device__ inline float bfhi(unsigned int u) { return __uint_as_float(u & 0xffff0000u); }

// ---------------- CSR build ----------------

__global__ void k_init(int* __restrict__ cnt, int* __restrict__ cursor) {
    int i = blockIdx.x * 256 + threadIdx.x;
    if (i < N_NODES) { cnt[i] = 0; cursor[i] = 0; }
}

__global__ void k_count(const int* __restrict__ dst, int* __restrict__ cnt) {
    int e = blockIdx.x * 256 + threadIdx.x;
    if (e < N_EDGES) atomicAdd(&cnt[dst[e]], 1);
}

__global__ void k_scan_partial(const int* __restrict__ cnt, int* __restrict__ rowstart,
                               float* __restrict__ dinv, int* __restrict__ bsum) {
    __shared__ int wsum[4];
    int tid = threadIdx.x;
    int base = blockIdx.x * 1024 + tid * 4;
    int v[4];
#pragma unroll
    for (int j = 0; j < 4; j++) {
        int i = base + j;
        v[j] = (i < N_NODES) ? cnt[i] : 0;
        if (i < N_NODES) dinv[i] = rsqrtf((float)v[j] + 1.0f);  // +1 self-loop
    }
    int t = v[0] + v[1] + v[2] + v[3];
    int lane = tid & 63, wave = tid >> 6;
    int incl = t;
#pragma unroll
    for (int off = 1; off < 64; off <<= 1) {
        int u = __shfl_up(incl, off);
        if (lane >= off) incl += u;
    }
    if (lane == 63) wsum[wave] = incl;
    __syncthreads();
    int woff = 0;
    for (int w = 0; w < wave; w++) woff += wsum[w];
    int run = woff + incl - t;
#pragma unroll
    for (int j = 0; j < 4; j++) {
        int i = base + j;
        if (i < N_NODES) rowstart[i] = run;
        run += v[j];
    }
    if (tid == 255) bsum[blockIdx.x] = woff + incl;
}

__global__ void k_scan_blocks(const int* __restrict__ bsum, int* __restrict__ boff,
                              int* __restrict__ rowstart, int nb) {
    __shared__ int wtot[2];
    int tid = threadIdx.x;
    int v = (tid < nb) ? bsum[tid] : 0;
    int lane = tid & 63, wave = tid >> 6;
    int incl = v;
#pragma unroll
    for (int off = 1; off < 64; off <<= 1) {
        int u = __shfl_up(incl, off);
        if (lane >= off) incl += u;
    }
    if (lane == 63) wtot[wave] = incl;
    __syncthreads();
    int excl = incl - v + (wave ? wtot[0] : 0);
    if (tid < nb) boff[tid] = excl;
    if (tid == 0) rowstart[N_NODES] = N_EDGES;
}

__global__ void k_add_off(int* __restrict__ rowstart, const int* __restrict__ boff) {
    int base = blockIdx.x * 1024 + threadIdx.x * 4;
    int off = boff[blockIdx.x];
#pragma unroll
    for (int j = 0; j < 4; j++) {
        int i = base + j;
        if (i < N_NODES) rowstart[i] += off;
    }
}

__global__ void k_fill(const int* __restrict__ src, const int* __restrict__ dst,
                       const int* __restrict__ rowstart, int* __restrict__ cursor,
                       int* __restrict__ esrc) {
    int e = blockIdx.x * 256 + threadIdx.x;
    if (e < N_EDGES) {
        int d = dst[e];
        int p = rowstart[d] + atomicAdd(&cursor[d], 1);
        esrc[p] = src[e];
    }
}

// ---------------- casts / weight prep ----------------

__global__ void k_cast_x(const float* __restrict__ x, uint2* __restrict__ xb) {
    int i = blockIdx.x * 256 + threadIdx.x;  // 4 floats per thread, 12.8M total
    float4 v = ((const float4*)x)[i];
    unsigned int lo = (unsigned int)f2bf(v.x) | ((unsigned int)f2bf(v.y) << 16);
    unsigned int hi = (unsigned int)f2bf(v.z) | ((unsigned int)f2bf(v.w) << 16);
    xb[i] = make_uint2(lo, hi);
}

// W1T[n][k] = bf16(W1[k][n]), [256][128]
__global__ void k_prep_w1(const float* __restrict__ W1, unsigned short* __restrict__ W1T) {
    int i = blockIdx.x * 256 + threadIdx.x;  // 32768
    int n = i >> 7, k = i & 127;
    W1T[i] = f2bf(W1[k * F_HID + n]);
}

// W2T[n][k] = bf16(W2[k][n]) for n<40 else 0, [64][256]
__global__ void k_prep_w2(const float* __restrict__ W2, unsigned short* __restrict__ W2T) {
    int i = blockIdx.x * 256 + threadIdx.x;  // 16384
    int n = i >> 8, k = i & 255;
    W2T[i] = (n < F_OUT) ? f2bf(W2[k * F_OUT + n]) : (unsigned short)0;
}

// ---------------- layer 1 aggregation (bf16 x, fp32 accum, bf16 out) ----------------
__global__ void k_agg1(const unsigned int* __restrict__ xb, const float* __restrict__ dinv,
                       const int* __restrict__ rowstart, const int* __restrict__ esrc,
                       unsigned int* __restrict__ xagg) {
    int node = blockIdx.x * 4 + (threadIdx.x >> 6);
    int lane = threadIdx.x & 63;
    float di = dinv[node];
    unsigned int v = xb[node * 64 + lane];
    float ax = di * bflo(v), ay = di * bfhi(v);  // self-loop
    int e0 = rowstart[node], e1 = rowstart[node + 1];
    int e = e0;
    for (; e + 1 < e1; e += 2) {
        int s0 = esrc[e], s1 = esrc[e + 1];
        float w0 = dinv[s0], w1 = dinv[s1];
        unsigned int u0 = xb[s0 * 64 + lane];
        unsigned int u1 = xb[s1 * 64 + lane];
        ax += w0 * bflo(u0) + w1 * bflo(u1);
        ay += w0 * bfhi(u0) + w1 * bfhi(u1);
    }
    if (e < e1) {
        int s = esrc[e];
        float w = dinv[s];
        unsigned int u = xb[s * 64 + lane];
        ax += w * bflo(u);
        ay += w * bfhi(u);
    }
    ax *= di; ay *= di;
    xagg[node * 64 + lane] = (unsigned int)f2bf(ax) | ((unsigned int)f2bf(ay) << 16);
}

// ---------------- GEMM1: h = bf16(relu(xagg @ W1 + b1)), MFMA 16x16x32 ----------------
// tile 128x128, BK=64, 4 waves each 64x64 (4x4 frags)
__launch_bounds__(256)
__global__ void k_gemm1(const unsigned short* __restrict__ A,   // xagg bf16 [M][128]
                        const unsigned short* __restrict__ BT,  // W1T bf16 [256][128]
                        const float* __restrict__ bias,
                        unsigned short* __restrict__ H) {       // h bf16 [M][256]
    __shared__ __align__(16) unsigned short As[128][72];
    __shared__ __align__(16) unsigned short Bs[128][72];
    int tid = threadIdx.x;
    int row0 = blockIdx.x * 128, col0 = blockIdx.y * 128;
    int w = tid >> 6, lane = tid & 63;
    int wm = w & 1, wn = w >> 1;
    int quad = lane >> 4, l16 = lane & 15;
    f32x4 acc[4][4];
#pragma unroll
    for (int i = 0; i < 4; i++)
#pragma unroll
        for (int j = 0; j < 4; j++) acc[i][j] = (f32x4){0.f, 0.f, 0.f, 0.f};

    for (int kc = 0; kc < 2; ++kc) {
        int k0 = kc * 64;
        __syncthreads();
#pragma unroll
        for (int i = 0; i < 4; i++) {  // A: 128 rows x 64 k
            int flat = i * 256 + tid;
            int r = flat >> 3, ko = (flat & 7) * 8;
            int row = row0 + r;
            uint4 val = make_uint4(0, 0, 0, 0);
            if (row < N_NODES) val = *(const uint4*)(A + (size_t)row * F_IN + k0 + ko);
            *(uint4*)&As[r][ko] = val;
        }
#pragma unroll
        for (int i = 0; i < 4; i++) {  // B: 128 cols x 64 k
            int flat = i * 256 + tid;
            int n = flat >> 3, ko = (flat & 7) * 8;
            *(uint4*)&Bs[n][ko] = *(const uint4*)(BT + (size_t)(col0 + n) * F_IN + k0 + ko);
        }
        __syncthreads();
#pragma unroll
        for (int ks = 0; ks < 2; ks++) {
            int koff = ks * 32 + quad * 8;
            bf16x8 af[4], bf[4];
#pragma unroll
            for (int i = 0; i < 4; i++) af[i] = *(const bf16x8*)&As[wm * 64 + i * 16 + l16][koff];
#pragma unroll
            for (int j = 0; j < 4; j++) bf[j] = *(const bf16x8*)&Bs[wn * 64 + j * 16 + l16][koff];
#pragma unroll
            for (int i = 0; i < 4; i++)
#pragma unroll
                for (int j = 0; j < 4; j++)
                    acc[i][j] = __builtin_amdgcn_mfma_f32_16x16x32_bf16(af[i], bf[j], acc[i][j], 0, 0, 0);
        }
    }
#pragma unroll
    for (int j = 0; j < 4; j++) {
        int gcol = col0 + wn * 64 + j * 16 + l16;
        float bj = bias[gcol];
#pragma unroll
        for (int i = 0; i < 4; i++) {
            int gr0 = row0 + wm * 64 + i * 16 + quad * 4;
#pragma unroll
            for (int r = 0; r < 4; r++) {
                int grow = gr0 + r;
                if (grow < N_NODES) {
                    float val = fmaxf(acc[i][j][r] + bj, 0.0f);
                    H[(size_t)grow * F_HID + gcol] = f2bf(val);
                }
            }
        }
    }
}

// ---------------- GEMM2: h2 = h @ W2 (fp32 out), MFMA, tile 256x64, BK=64 ----------------
__launch_bounds__(256)
__global__ void k_gemm2(const unsigned short* __restrict__ A,   // h bf16 [M][256]
                        const unsigned short* __restrict__ BT,  // W2T bf16 [64][256]
                        float* __restrict__ C) {                // h2 fp32 [M][40]
    __shared__ __align__(16) unsigned short As[256][72];
    __shared__ __align__(16) unsigned short Bs[64][72];
    int tid = threadIdx.x;
    int row0 = blockIdx.x * 256;
    int w = tid >> 6, lane = tid & 63;
    int quad = lane >> 4, l16 = lane & 15;
    f32x4 acc[4][4];
#pragma unroll
    for (int i = 0; i < 4; i++)
#pragma unroll
        for (int j = 0; j < 4; j++) acc[i][j] = (f32x4){0.f, 0.f, 0.f, 0.f};

    for (int kc = 0; kc < 4; ++kc) {
        int k0 = kc * 64;
        __syncthreads();
#pragma unroll
        for (int i = 0; i < 8; i++) {  // A: 256 rows x 64 k
            int flat = i * 256 + tid;
            int r = flat >> 3, ko = (flat & 7) * 8;
            int row = row0 + r;
            uint4 val = make_uint4(0, 0, 0, 0);
            if (row < N_NODES) val = *(const uint4*)(A + (size_t)row * F_HID + k0 + ko);
            *(uint4*)&As[r][ko] = val;
        }
        {
            int flat = tid;  // B: 64 cols x 64 k = 512 chunks, first 2 waves... use 2 iters over 256 thr
#pragma unroll
            for (int i = 0; i < 2; i++) {
                int f2 = i * 256 + flat;
                int n = f2 >> 3, ko = (f2 & 7) * 8;
                *(uint4*)&Bs[n][ko] = *(const uint4*)(BT + (size_t)n * F_HID + k0 + ko);
            }
        }
        __syncthreads();
#pragma unroll
        for (int ks = 0; ks < 2; ks++) {
            int koff = ks * 32 + quad * 8;
            bf16x8 af[4], bf[4];
#pragma unroll
            for (int i = 0; i < 4; i++) af[i] = *(const bf16x8*)&As[w * 64 + i * 16 + l16][koff];
#pragma unroll
            for (int j = 0; j < 4; j++) bf[j] = *(const bf16x8*)&Bs[j * 16 + l16][koff];
#pragma unroll
            for (int i = 0; i < 4; i++)
#pragma unroll
                for (int j = 0; j < 4; j++)
                    acc[i][j] = __builtin_amdgcn_mfma_f32_16x16x32_bf16(af[i], bf[j], acc[i][j], 0, 0, 0);
        }
    }
#pragma unroll
    for (int j = 0; j < 3; j++) {  // cols 0..47 cover the 40 real ones
        int col = j * 16 + l16;
        if (col < F_OUT) {
#pragma unroll
            for (int i = 0; i < 4; i++) {
                int gr0 = row0 + w * 64 + i * 16 + quad * 4;
#pragma unroll
                for (int r = 0; r < 4; r++) {
                    int grow = gr0 + r;
                    if (grow < N_NODES) C[(size_t)grow * F_OUT + col] = acc[i][j][r];
                }
            }
        }
    }
}

// ---------------- layer 2 aggregation + bias + log_softmax ----------------
__global__ void k_agg2(const float* __restrict__ h2, const float* __restrict__ dinv,
                       const int* __restrict__ rowstart, const int* __restrict__ esrc,
                       const float* __restrict__ b2, float* __restrict__ out) {
    int node = blockIdx.x * 4 + (threadIdx.x >> 6);
    int lane = threadIdx.x & 63;
    float di = dinv[node];
    bool act = lane < F_OUT;
    int li = act ? lane : 0;
    float acc = act ? di * h2[(size_t)node * F_OUT + lane] : 0.0f;
    int e0 = rowstart[node], e1 = rowstart[node + 1];
    int e = e0;
    for (; e + 1 < e1; e += 2) {
        int s0 = esrc[e], s1 = esrc[e + 1];
        float w0 = dinv[s0], w1 = dinv[s1];
        float v0 = h2[(size_t)s0 * F_OUT + li];
        float v1 = h2[(size_t)s1 * F_OUT + li];
        if (act) acc += w0 * v0 + w1 * v1;
    }
    if (e < e1) {
        int s = esrc[e];
        float w = dinv[s];
        float v = h2[(size_t)s * F_OUT + li];
        if (act) acc += w * v;
    }
    float val = act ? (di * acc + b2[li]) : -3.0e38f;
    float m = val;
#pragma unroll
    for (int off = 32; off; off >>= 1) m = fmaxf(m, __shfl_xor(m, off));
    float ex = act ? expf(val - m) : 0.0f;
    float ssum = ex;
#pragma unroll
    for (int off = 32; off; off >>= 1) ssum += __shfl_xor(ssum, off);
    if (act) out[(size_t)node * F_OUT + lane] = val - m - logf(ssum);
}

// ---------------- launch ----------------

extern "C" void kernel_launch(void* const* d_in, const int* in_sizes, int n_in,
                              void* d_out, int out_size, void* d_ws, size_t ws_size,
                              hipStream_t stream) {
    const float* x  = (const float*)d_in[0];
    const int* edge = (const int*)d_in[1];
    const float* W1 = (const float*)d_in[2];
    const float* b1 = (const float*)d_in[3];
    const float* W2 = (const float*)d_in[4];
    const float* b2 = (const float*)d_in[5];
    float* out = (float*)d_out;
    const int* src = edge;
    const int* dst = edge + N_EDGES;

    char* ws = (char*)d_ws;
    size_t off = 0;
    auto alloc = [&](size_t bytes) -> void* {
        void* p = ws + off;
        off = (off + bytes + 255) & ~(size_t)255;
        return p;
    };
    float* dinv   = (float*)alloc((size_t)N_NODES * 4);
    int* cnt      = (int*)alloc((size_t)N_NODES * 4);
    int* cursor   = (int*)alloc((size_t)N_NODES * 4);
    int* rowstart = (int*)alloc((size_t)(N_NODES + 1) * 4);
    int* bsum     = (int*)alloc(128 * 4);
    int* boff     = (int*)alloc(128 * 4);
    int* esrc     = (int*)alloc((size_t)N_EDGES * 4);
    unsigned int* xb     = (unsigned int*)alloc((size_t)N_NODES * F_IN * 2);  // bf16 25.6 MB
    unsigned int* xagg   = (unsigned int*)alloc((size_t)N_NODES * F_IN * 2);  // bf16 25.6 MB
    unsigned short* W1T  = (unsigned short*)alloc((size_t)F_HID * F_IN * 2);
    unsigned short* W2T  = (unsigned short*)alloc((size_t)64 * F_HID * 2);
    unsigned short* h    = (unsigned short*)alloc((size_t)N_NODES * F_HID * 2);  // 51.2 MB
    float* h2     = (float*)alloc((size_t)N_NODES * F_OUT * 4);  // 16 MB
    (void)ws_size; (void)in_sizes; (void)n_in; (void)out_size;

    int nb = (N_NODES + 1023) / 1024;  // 98

    hipLaunchKernelGGL(k_init, dim3((N_NODES + 255) / 256), dim3(256), 0, stream, cnt, cursor);
    hipLaunchKernelGGL(k_count, dim3((N_EDGES + 255) / 256), dim3(256), 0, stream, dst, cnt);
    hipLaunchKernelGGL(k_scan_partial, dim3(nb), dim3(256), 0, stream, cnt, rowstart, dinv, bsum);
    hipLaunchKernelGGL(k_scan_blocks, dim3(1), dim3(128), 0, stream, bsum, boff, rowstart, nb);
    hipLaunchKernelGGL(k_add_off, dim3(nb), dim3(256), 0, stream, rowstart, boff);
    hipLaunchKernelGGL(k_fill, dim3((N_EDGES + 255) / 256), dim3(256), 0, stream, src, dst, rowstart, cursor, esrc);
    hipLaunchKernelGGL(k_cast_x, dim3(N_NODES * F_IN / 4 / 256), dim3(256), 0, stream, x, (uint2*)xb);
    hipLaunchKernelGGL(k_prep_w1, dim3(F_HID * F_IN / 256), dim3(256), 0, stream, W1, W1T);
    hipLaunchKernelGGL(k_prep_w2, dim3(64 * F_HID / 256), dim3(256), 0, stream, W2, W2T);
    hipLaunchKernelGGL(k_agg1, dim3(N_NODES / 4), dim3(256), 0, stream, xb, dinv, rowstart, esrc, xagg);
    hipLaunchKernelGGL(k_gemm1, dim3(782, 2), dim3(256), 0, stream,
                       (const unsigned short*)xagg, W1T, b1, h);
    hipLaunchKernelGGL(k_gemm2, dim3(391), dim3(256), 0, stream, h, W2T, h2);
    hipLaunchKernelGGL(k_agg2, dim3(N_NODES / 4), dim3(256), 0, stream, h2, dinv, rowstart, esrc, b2, out);
}

// Round 3
// 362.459 us; speedup vs baseline: 1.6388x; 1.2408x over previous
//
#include <hip/hip_runtime.h>

#define N_NODES 100000
#define N_EDGES 1000000
#define F_IN 128
#define F_HID 256
#define F_OUT 40

typedef __attribute__((ext_vector_type(8))) short bf16x8;
typedef __attribute__((ext_vector_type(4))) float f32x4;

__device__ inline unsigned short f2bf(float f) {
    unsigned int u = __float_as_uint(f);
    return (unsigned short)((u + 0x7fffu + ((u >> 16) & 1u)) >> 16);
}
__device__ inline float bflo(unsigned int u) { return __uint_as_float(u << 16); }
__device__ inline float bfhi(unsigned int u) { return __uint_as_float(u & 0xffff0000u); }

// ---------------- CSR build ----------------

__global__ void k_count(const int* __restrict__ dst, int* __restrict__ cnt) {
    int e = blockIdx.x * 256 + threadIdx.x;
    if (e < N_EDGES) atomicAdd(&cnt[dst[e]], 1);
}

__global__ void k_scan_partial(const int* __restrict__ cnt, int* __restrict__ rowstart,
                               float* __restrict__ dinv, int* __restrict__ bsum) {
    __shared__ int wsum[4];
    int tid = threadIdx.x;
    int base = blockIdx.x * 1024 + tid * 4;
    int v[4];
#pragma unroll
    for (int j = 0; j < 4; j++) {
        int i = base + j;
        v[j] = (i < N_NODES) ? cnt[i] : 0;
        if (i < N_NODES) dinv[i] = rsqrtf((float)v[j] + 1.0f);  // +1 self-loop
    }
    int t = v[0] + v[1] + v[2] + v[3];
    int lane = tid & 63, wave = tid >> 6;
    int incl = t;
#pragma unroll
    for (int off = 1; off < 64; off <<= 1) {
        int u = __shfl_up(incl, off);
        if (lane >= off) incl += u;
    }
    if (lane == 63) wsum[wave] = incl;
    __syncthreads();
    int woff = 0;
    for (int w = 0; w < wave; w++) woff += wsum[w];
    int run = woff + incl - t;
#pragma unroll
    for (int j = 0; j < 4; j++) {
        int i = base + j;
        if (i < N_NODES) rowstart[i] = run;
        run += v[j];
    }
    if (tid == 255) bsum[blockIdx.x] = woff + incl;
}

__global__ void k_scan_blocks(const int* __restrict__ bsum, int* __restrict__ boff,
                              int* __restrict__ rowstart, int nb) {
    __shared__ int wtot[2];
    int tid = threadIdx.x;
    int v = (tid < nb) ? bsum[tid] : 0;
    int lane = tid & 63, wave = tid >> 6;
    int incl = v;
#pragma unroll
    for (int off = 1; off < 64; off <<= 1) {
        int u = __shfl_up(incl, off);
        if (lane >= off) incl += u;
    }
    if (lane == 63) wtot[wave] = incl;
    __syncthreads();
    int excl = incl - v + (wave ? wtot[0] : 0);
    if (tid < nb) boff[tid] = excl;
    if (tid == 0) rowstart[N_NODES] = N_EDGES;
}

__global__ void k_add_off(int* __restrict__ rowstart, const int* __restrict__ boff) {
    int base = blockIdx.x * 1024 + threadIdx.x * 4;
    int off = boff[blockIdx.x];
#pragma unroll
    for (int j = 0; j < 4; j++) {
        int i = base + j;
        if (i < N_NODES) rowstart[i] += off;
    }
}

__global__ void k_fill(const int* __restrict__ src, const int* __restrict__ dst,
                       const int* __restrict__ rowstart, int* __restrict__ cursor,
                       int* __restrict__ esrc) {
    int e = blockIdx.x * 256 + threadIdx.x;
    if (e < N_EDGES) {
        int d = dst[e];
        int p = rowstart[d] + atomicAdd(&cursor[d], 1);
        esrc[p] = src[e];
    }
}

// ---------------- casts / weight prep ----------------

__global__ void k_cast_x(const float* __restrict__ x, uint2* __restrict__ xb) {
    int i = blockIdx.x * 256 + threadIdx.x;  // 4 floats per thread
    float4 v = ((const float4*)x)[i];
    unsigned int lo = (unsigned int)f2bf(v.x) | ((unsigned int)f2bf(v.y) << 16);
    unsigned int hi = (unsigned int)f2bf(v.z) | ((unsigned int)f2bf(v.w) << 16);
    xb[i] = make_uint2(lo, hi);
}

// W1T[n][k] = bf16(W1[k][n]) [256][128];  W2T[n][k] = bf16(W2[k][n]) [64][256]
__global__ void k_prep_w(const float* __restrict__ W1, const float* __restrict__ W2,
                         unsigned short* __restrict__ W1T, unsigned short* __restrict__ W2T) {
    int i = blockIdx.x * 256 + threadIdx.x;  // 32768 + 16384 = 49152
    if (i < 32768) {
        int n = i >> 7, k = i & 127;
        W1T[i] = f2bf(W1[k * F_HID + n]);
    } else {
        int j = i - 32768;
        int n = j >> 8, k = j & 255;
        W2T[j] = (n < F_OUT) ? f2bf(W2[k * F_OUT + n]) : (unsigned short)0;
    }
}

// ---------------- layer 1 aggregation: 32-lane group per node, 2 nodes/wave ----------------
__global__ void k_agg1(const uint2* __restrict__ xb2, const float* __restrict__ dinv,
                       const int* __restrict__ rowstart, const int* __restrict__ esrc,
                       uint2* __restrict__ xagg2) {
    int node = blockIdx.x * 8 + (threadIdx.x >> 5);
    int l32 = threadIdx.x & 31;
    float di = dinv[node];
    uint2 v = xb2[(size_t)node * 32 + l32];
    float a0 = di * bflo(v.x), a1 = di * bfhi(v.x);
    float a2 = di * bflo(v.y), a3 = di * bfhi(v.y);
    int e0 = rowstart[node], e1 = rowstart[node + 1];
    int e = e0;
    for (; e + 3 < e1; e += 4) {
        int s0 = esrc[e], s1 = esrc[e + 1], s2 = esrc[e + 2], s3 = esrc[e + 3];
        float w0 = dinv[s0], w1 = dinv[s1], w2 = dinv[s2], w3 = dinv[s3];
        uint2 u0 = xb2[(size_t)s0 * 32 + l32];
        uint2 u1 = xb2[(size_t)s1 * 32 + l32];
        uint2 u2 = xb2[(size_t)s2 * 32 + l32];
        uint2 u3 = xb2[(size_t)s3 * 32 + l32];
        a0 += w0 * bflo(u0.x) + w1 * bflo(u1.x) + w2 * bflo(u2.x) + w3 * bflo(u3.x);
        a1 += w0 * bfhi(u0.x) + w1 * bfhi(u1.x) + w2 * bfhi(u2.x) + w3 * bfhi(u3.x);
        a2 += w0 * bflo(u0.y) + w1 * bflo(u1.y) + w2 * bflo(u2.y) + w3 * bflo(u3.y);
        a3 += w0 * bfhi(u0.y) + w1 * bfhi(u1.y) + w2 * bfhi(u2.y) + w3 * bfhi(u3.y);
    }
    for (; e < e1; ++e) {
        int s = esrc[e];
        float w = dinv[s];
        uint2 u = xb2[(size_t)s * 32 + l32];
        a0 += w * bflo(u.x);
        a1 += w * bfhi(u.x);
        a2 += w * bflo(u.y);
        a3 += w * bfhi(u.y);
    }
    a0 *= di; a1 *= di; a2 *= di; a3 *= di;
    uint2 o;
    o.x = (unsigned int)f2bf(a0) | ((unsigned int)f2bf(a1) << 16);
    o.y = (unsigned int)f2bf(a2) | ((unsigned int)f2bf(a3) << 16);
    xagg2[(size_t)node * 32 + l32] = o;
}

// ---------------- GEMM1: h = bf16(relu(xagg @ W1 + b1)), MFMA 16x16x32 ----------------
__launch_bounds__(256)
__global__ void k_gemm1(const unsigned short* __restrict__ A,   // xagg bf16 [M][128]
                        const unsigned short* __restrict__ BT,  // W1T bf16 [256][128]
                        const float* __restrict__ bias,
                        unsigned short* __restrict__ H) {       // h bf16 [M][256]
    __shared__ __align__(16) unsigned short As[128][72];
    __shared__ __align__(16) unsigned short Bs[128][72];
    int tid = threadIdx.x;
    int row0 = blockIdx.x * 128, col0 = blockIdx.y * 128;
    int w = tid >> 6, lane = tid & 63;
    int wm = w & 1, wn = w >> 1;
    int quad = lane >> 4, l16 = lane & 15;
    f32x4 acc[4][4];
#pragma unroll
    for (int i = 0; i < 4; i++)
#pragma unroll
        for (int j = 0; j < 4; j++) acc[i][j] = (f32x4){0.f, 0.f, 0.f, 0.f};

    for (int kc = 0; kc < 2; ++kc) {
        int k0 = kc * 64;
        __syncthreads();
#pragma unroll
        for (int i = 0; i < 4; i++) {
            int flat = i * 256 + tid;
            int r = flat >> 3, ko = (flat & 7) * 8;
            int row = row0 + r;
            uint4 val = make_uint4(0, 0, 0, 0);
            if (row < N_NODES) val = *(const uint4*)(A + (size_t)row * F_IN + k0 + ko);
            *(uint4*)&As[r][ko] = val;
        }
#pragma unroll
        for (int i = 0; i < 4; i++) {
            int flat = i * 256 + tid;
            int n = flat >> 3, ko = (flat & 7) * 8;
            *(uint4*)&Bs[n][ko] = *(const uint4*)(BT + (size_t)(col0 + n) * F_IN + k0 + ko);
        }
        __syncthreads();
#pragma unroll
        for (int ks = 0; ks < 2; ks++) {
            int koff = ks * 32 + quad * 8;
            bf16x8 af[4], bf[4];
#pragma unroll
            for (int i = 0; i < 4; i++) af[i] = *(const bf16x8*)&As[wm * 64 + i * 16 + l16][koff];
#pragma unroll
            for (int j = 0; j < 4; j++) bf[j] = *(const bf16x8*)&Bs[wn * 64 + j * 16 + l16][koff];
#pragma unroll
            for (int i = 0; i < 4; i++)
#pragma unroll
                for (int j = 0; j < 4; j++)
                    acc[i][j] = __builtin_amdgcn_mfma_f32_16x16x32_bf16(af[i], bf[j], acc[i][j], 0, 0, 0);
        }
    }
#pragma unroll
    for (int j = 0; j < 4; j++) {
        int gcol = col0 + wn * 64 + j * 16 + l16;
        float bj = bias[gcol];
#pragma unroll
        for (int i = 0; i < 4; i++) {
            int gr0 = row0 + wm * 64 + i * 16 + quad * 4;
#pragma unroll
            for (int r = 0; r < 4; r++) {
                int grow = gr0 + r;
                if (grow < N_NODES) {
                    float val = fmaxf(acc[i][j][r] + bj, 0.0f);
                    H[(size_t)grow * F_HID + gcol] = f2bf(val);
                }
            }
        }
    }
}

// ---------------- GEMM2: h2b = bf16(h @ W2), [M][64] padded, MFMA ----------------
__launch_bounds__(256)
__global__ void k_gemm2(const unsigned short* __restrict__ A,   // h bf16 [M][256]
                        const unsigned short* __restrict__ BT,  // W2T bf16 [64][256]
                        unsigned short* __restrict__ C) {       // h2b bf16 [M][64]
    __shared__ __align__(16) unsigned short As[256][72];
    __shared__ __align__(16) unsigned short Bs[64][72];
    int tid = threadIdx.x;
    int row0 = blockIdx.x * 256;
    int w = tid >> 6, lane = tid & 63;
    int quad = lane >> 4, l16 = lane & 15;
    f32x4 acc[4][3];
#pragma unroll
    for (int i = 0; i < 4; i++)
#pragma unroll
        for (int j = 0; j < 3; j++) acc[i][j] = (f32x4){0.f, 0.f, 0.f, 0.f};

    for (int kc = 0; kc < 4; ++kc) {
        int k0 = kc * 64;
        __syncthreads();
#pragma unroll
        for (int i = 0; i < 8; i++) {
            int flat = i * 256 + tid;
            int r = flat >> 3, ko = (flat & 7) * 8;
            int row = row0 + r;
            uint4 val = make_uint4(0, 0, 0, 0);
            if (row < N_NODES) val = *(const uint4*)(A + (size_t)row * F_HID + k0 + ko);
            *(uint4*)&As[r][ko] = val;
        }
#pragma unroll
        for (int i = 0; i < 2; i++) {
            int f2 = i * 256 + tid;
            int n = f2 >> 3, ko = (f2 & 7) * 8;
            *(uint4*)&Bs[n][ko] = *(const uint4*)(BT + (size_t)n * F_HID + k0 + ko);
        }
        __syncthreads();
#pragma unroll
        for (int ks = 0; ks < 2; ks++) {
            int koff = ks * 32 + quad * 8;
            bf16x8 af[4], bf[3];
#pragma unroll
            for (int i = 0; i < 4; i++) af[i] = *(const bf16x8*)&As[w * 64 + i * 16 + l16][koff];
#pragma unroll
            for (int j = 0; j < 3; j++) bf[j] = *(const bf16x8*)&Bs[j * 16 + l16][koff];
#pragma unroll
            for (int i = 0; i < 4; i++)
#pragma unroll
                for (int j = 0; j < 3; j++)
                    acc[i][j] = __builtin_amdgcn_mfma_f32_16x16x32_bf16(af[i], bf[j], acc[i][j], 0, 0, 0);
        }
    }
#pragma unroll
    for (int j = 0; j < 3; j++) {
        int col = j * 16 + l16;
        if (col < F_OUT) {
#pragma unroll
            for (int i = 0; i < 4; i++) {
                int gr0 = row0 + w * 64 + i * 16 + quad * 4;
#pragma unroll
                for (int r = 0; r < 4; r++) {
                    int grow = gr0 + r;
                    if (grow < N_NODES) C[(size_t)grow * 64 + col] = f2bf(acc[i][j][r]);
                }
            }
        }
    }
}

// ---------------- layer 2 aggregation + bias + log_softmax ----------------
// 32-lane group per node, 2 nodes/wave; lane l<20 holds feature pair (2l, 2l+1)
__global__ void k_agg2(const unsigned int* __restrict__ h2v,  // bf16 [M][64] as uint [M][32]
                       const float* __restrict__ dinv,
                       const int* __restrict__ rowstart, const int* __restrict__ esrc,
                       const float* __restrict__ b2, float* __restrict__ out) {
    int node = blockIdx.x * 8 + (threadIdx.x >> 5);
    int l32 = threadIdx.x & 31;
    bool act = l32 < 20;
    float di = dinv[node];
    float acc0 = 0.0f, acc1 = 0.0f;
    if (act) {
        unsigned int u = h2v[(size_t)node * 32 + l32];
        acc0 = di * bflo(u);
        acc1 = di * bfhi(u);
    }
    int e0 = rowstart[node], e1 = rowstart[node + 1];
    int e = e0;
    for (; e + 3 < e1; e += 4) {
        int s0 = esrc[e], s1 = esrc[e + 1], s2 = esrc[e + 2], s3 = esrc[e + 3];
        float w0 = dinv[s0], w1 = dinv[s1], w2 = dinv[s2], w3 = dinv[s3];
        if (act) {
            unsigned int u0 = h2v[(size_t)s0 * 32 + l32];
            unsigned int u1 = h2v[(size_t)s1 * 32 + l32];
            unsigned int u2 = h2v[(size_t)s2 * 32 + l32];
            unsigned int u3 = h2v[(size_t)s3 * 32 + l32];
            acc0 += w0 * bflo(u0) + w1 * bflo(u1) + w2 * bflo(u2) + w3 * bflo(u3);
            acc1 += w0 * bfhi(u0) + w1 * bfhi(u1) + w2 * bfhi(u2) + w3 * bfhi(u3);
        }
    }
    for (; e < e1; ++e) {
        int s = esrc[e];
        float w = dinv[s];
        if (act) {
            unsigned int u = h2v[(size_t)s * 32 + l32];
            acc0 += w * bflo(u);
            acc1 += w * bfhi(u);
        }
    }
    float val0 = -3.0e38f, val1 = -3.0e38f;
    if (act) {
        float2 bb = ((const float2*)b2)[l32];
        val0 = di * acc0 + bb.x;
        val1 = di * acc1 + bb.y;
    }
    float m = fmaxf(val0, val1);
#pragma unroll
    for (int off = 16; off; off >>= 1) m = fmaxf(m, __shfl_xor(m, off));
    float ex = act ? (__expf(val0 - m) + __expf(val1 - m)) : 0.0f;
    float ssum = ex;
#pragma unroll
    for (int off = 16; off; off >>= 1) ssum += __shfl_xor(ssum, off);
    float logs = logf(ssum);
    if (act) {
        float2 o = make_float2(val0 - m - logs, val1 - m - logs);
        ((float2*)(out + (size_t)node * F_OUT))[l32] = o;
    }
}

// ---------------- launch ----------------

extern "C" void kernel_launch(void* const* d_in, const int* in_sizes, int n_in,
                              void* d_out, int out_size, void* d_ws, size_t ws_size,
                              hipStream_t stream) {
    const float* x  = (const float*)d_in[0];
    const int* edge = (const int*)d_in[1];
    const float* W1 = (const float*)d_in[2];
    const float* b1 = (const float*)d_in[3];
    const float* W2 = (const float*)d_in[4];
    const float* b2 = (const float*)d_in[5];
    float* out = (float*)d_out;
    const int* src = edge;
    const int* dst = edge + N_EDGES;

    char* ws = (char*)d_ws;
    size_t off = 0;
    auto alloc = [&](size_t bytes) -> void* {
        void* p = ws + off;
        off = (off + bytes + 255) & ~(size_t)255;
        return p;
    };
    float* dinv   = (float*)alloc((size_t)N_NODES * 4);
    int* cnt      = (int*)alloc((size_t)N_NODES * 4);
    int* cursor   = (int*)alloc((size_t)N_NODES * 4);
    int* rowstart = (int*)alloc((size_t)(N_NODES + 1) * 4);
    int* bsum     = (int*)alloc(128 * 4);
    int* boff     = (int*)alloc(128 * 4);
    int* esrc     = (int*)alloc((size_t)N_EDGES * 4);
    unsigned int* xb     = (unsigned int*)alloc((size_t)N_NODES * F_IN * 2);  // bf16 25.6 MB
    unsigned int* xagg   = (unsigned int*)alloc((size_t)N_NODES * F_IN * 2);  // bf16 25.6 MB
    unsigned short* W1T  = (unsigned short*)alloc((size_t)F_HID * F_IN * 2);
    unsigned short* W2T  = (unsigned short*)alloc((size_t)64 * F_HID * 2);
    unsigned short* h    = (unsigned short*)alloc((size_t)N_NODES * F_HID * 2);  // 51.2 MB
    unsigned short* h2b  = (unsigned short*)alloc((size_t)N_NODES * 64 * 2);     // 12.8 MB
    (void)ws_size; (void)in_sizes; (void)n_in; (void)out_size;

    int nb = (N_NODES + 1023) / 1024;  // 98

    hipMemsetAsync(cnt, 0, (size_t)N_NODES * 4, stream);
    hipMemsetAsync(cursor, 0, (size_t)N_NODES * 4, stream);
    hipLaunchKernelGGL(k_count, dim3((N_EDGES + 255) / 256), dim3(256), 0, stream, dst, cnt);
    hipLaunchKernelGGL(k_scan_partial, dim3(nb), dim3(256), 0, stream, cnt, rowstart, dinv, bsum);
    hipLaunchKernelGGL(k_scan_blocks, dim3(1), dim3(128), 0, stream, bsum, boff, rowstart, nb);
    hipLaunchKernelGGL(k_add_off, dim3(nb), dim3(256), 0, stream, rowstart, boff);
    hipLaunchKernelGGL(k_fill, dim3((N_EDGES + 255) / 256), dim3(256), 0, stream, src, dst, rowstart, cursor, esrc);
    hipLaunchKernelGGL(k_cast_x, dim3(N_NODES * F_IN / 4 / 256), dim3(256), 0, stream, x, (uint2*)xb);
    hipLaunchKernelGGL(k_prep_w, dim3(192), dim3(256), 0, stream, W1, W2, W1T, W2T);
    hipLaunchKernelGGL(k_agg1, dim3(N_NODES / 8), dim3(256), 0, stream,
                       (const uint2*)xb, dinv, rowstart, esrc, (uint2*)xagg);
    hipLaunchKernelGGL(k_gemm1, dim3(782, 2), dim3(256), 0, stream,
                       (const unsigned short*)xagg, W1T, b1, h);
    hipLaunchKernelGGL(k_gemm2, dim3(391), dim3(256), 0, stream, h, W2T, h2b);
    hipLaunchKernelGGL(k_agg2, dim3(N_NODES / 8), dim3(256), 0, stream,
                       (const unsigned int*)h2b, dinv, rowstart, esrc, b2, out);
}

// Round 4
// 332.400 us; speedup vs baseline: 1.7870x; 1.0904x over previous
//
#include <hip/hip_runtime.h>

#define N_NODES 100000
#define N_EDGES 1000000
#define F_IN 128
#define F_HID 256
#define F_OUT 40
#define GROUP_NODES 12500  // N_NODES / 8 XCD-partition for the CSR fill

typedef __attribute__((ext_vector_type(8))) short bf16x8;
typedef __attribute__((ext_vector_type(4))) float f32x4;

__device__ inline unsigned short f2bf(float f) {
    unsigned int u = __float_as_uint(f);
    return (unsigned short)((u + 0x7fffu + ((u >> 16) & 1u)) >> 16);
}
__device__ inline float bflo(unsigned int u) { return __uint_as_float(u << 16); }
__device__ inline float bfhi(unsigned int u) { return __uint_as_float(u & 0xffff0000u); }

// ---------------- CSR build ----------------

// count + record each edge's slot within its dst bucket (atomic return value)
__global__ void k_count2(const int* __restrict__ dst, int* __restrict__ cnt,
                         int* __restrict__ slot) {
    int e = blockIdx.x * 256 + threadIdx.x;
    if (e < N_EDGES) slot[e] = atomicAdd(&cnt[dst[e]], 1);
}

__global__ void k_scan_partial(const int* __restrict__ cnt, int* __restrict__ rowstart,
                               float* __restrict__ dinv, int* __restrict__ bsum) {
    __shared__ int wsum[4];
    int tid = threadIdx.x;
    int base = blockIdx.x * 1024 + tid * 4;
    int v[4];
#pragma unroll
    for (int j = 0; j < 4; j++) {
        int i = base + j;
        v[j] = (i < N_NODES) ? cnt[i] : 0;
        if (i < N_NODES) dinv[i] = rsqrtf((float)v[j] + 1.0f);  // +1 self-loop
    }
    int t = v[0] + v[1] + v[2] + v[3];
    int lane = tid & 63, wave = tid >> 6;
    int incl = t;
#pragma unroll
    for (int off = 1; off < 64; off <<= 1) {
        int u = __shfl_up(incl, off);
        if (lane >= off) incl += u;
    }
    if (lane == 63) wsum[wave] = incl;
    __syncthreads();
    int woff = 0;
    for (int w = 0; w < wave; w++) woff += wsum[w];
    int run = woff + incl - t;
#pragma unroll
    for (int j = 0; j < 4; j++) {
        int i = base + j;
        if (i < N_NODES) rowstart[i] = run;
        run += v[j];
    }
    if (tid == 255) bsum[blockIdx.x] = woff + incl;
}

__global__ void k_scan_blocks(const int* __restrict__ bsum, int* __restrict__ boff,
                              int* __restrict__ rowstart, int nb) {
    __shared__ int wtot[2];
    int tid = threadIdx.x;
    int v = (tid < nb) ? bsum[tid] : 0;
    int lane = tid & 63, wave = tid >> 6;
    int incl = v;
#pragma unroll
    for (int off = 1; off < 64; off <<= 1) {
        int u = __shfl_up(incl, off);
        if (lane >= off) incl += u;
    }
    if (lane == 63) wtot[wave] = incl;
    __syncthreads();
    int excl = incl - v + (wave ? wtot[0] : 0);
    if (tid < nb) boff[tid] = excl;
    if (tid == 0) rowstart[N_NODES] = N_EDGES;
}

__global__ void k_add_off(int* __restrict__ rowstart, const int* __restrict__ boff) {
    int base = blockIdx.x * 1024 + threadIdx.x * 4;
    int off = boff[blockIdx.x];
#pragma unroll
    for (int j = 0; j < 4; j++) {
        int i = base + j;
        if (i < N_NODES) rowstart[i] += off;
    }
}

// XCD-partitioned, atomic-free fill: group g = blockIdx&7 owns dst range
// [g*GROUP_NODES, (g+1)*GROUP_NODES) -> its esrc window is a private ~512 KB
// span, so scatter lines stay in one XCD's L2 and evict once.
__global__ void k_fill2(const int* __restrict__ src, const int* __restrict__ dst,
                        const int* __restrict__ slot, const int* __restrict__ rowstart,
                        int* __restrict__ esrc) {
    int g = blockIdx.x & 7;
    int bg = blockIdx.x >> 3;
    int nbg = gridDim.x >> 3;
    int lo = g * GROUP_NODES;
    int hi = lo + GROUP_NODES;  // N_NODES = 8*GROUP_NODES exactly
    for (int base = (bg * 256 + threadIdx.x) * 4; base < N_EDGES; base += nbg * 1024) {
        int4 d4 = *(const int4*)(dst + base);
#pragma unroll
        for (int j = 0; j < 4; j++) {
            int d = (&d4.x)[j];
            if (d >= lo && d < hi) {
                int s = src[base + j];
                int sl = slot[base + j];
                esrc[rowstart[d] + sl] = s;
            }
        }
    }
}

// ---------------- casts / weight prep ----------------

__global__ void k_cast_x(const float* __restrict__ x, uint2* __restrict__ xb) {
    int i = blockIdx.x * 256 + threadIdx.x;  // 4 floats per thread
    float4 v = ((const float4*)x)[i];
    unsigned int lo = (unsigned int)f2bf(v.x) | ((unsigned int)f2bf(v.y) << 16);
    unsigned int hi = (unsigned int)f2bf(v.z) | ((unsigned int)f2bf(v.w) << 16);
    xb[i] = make_uint2(lo, hi);
}

// W1T[n][k] = bf16(W1[k][n]) [256][128];  W2T[n][k] = bf16(W2[k][n]) [64][256]
__global__ void k_prep_w(const float* __restrict__ W1, const float* __restrict__ W2,
                         unsigned short* __restrict__ W1T, unsigned short* __restrict__ W2T) {
    int i = blockIdx.x * 256 + threadIdx.x;  // 32768 + 16384 = 49152
    if (i < 32768) {
        int n = i >> 7, k = i & 127;
        W1T[i] = f2bf(W1[k * F_HID + n]);
    } else {
        int j = i - 32768;
        int n = j >> 8, k = j & 255;
        W2T[j] = (n < F_OUT) ? f2bf(W2[k * F_OUT + n]) : (unsigned short)0;
    }
}

// ---------------- layer 1 aggregation: 32-lane group per node, 2 nodes/wave ----------------
__global__ void k_agg1(const uint2* __restrict__ xb2, const float* __restrict__ dinv,
                       const int* __restrict__ rowstart, const int* __restrict__ esrc,
                       uint2* __restrict__ xagg2) {
    int node = blockIdx.x * 8 + (threadIdx.x >> 5);
    int l32 = threadIdx.x & 31;
    float di = dinv[node];
    uint2 v = xb2[(size_t)node * 32 + l32];
    float a0 = di * bflo(v.x), a1 = di * bfhi(v.x);
    float a2 = di * bflo(v.y), a3 = di * bfhi(v.y);
    int e0 = rowstart[node], e1 = rowstart[node + 1];
    int e = e0;
    for (; e + 3 < e1; e += 4) {
        int s0 = esrc[e], s1 = esrc[e + 1], s2 = esrc[e + 2], s3 = esrc[e + 3];
        float w0 = dinv[s0], w1 = dinv[s1], w2 = dinv[s2], w3 = dinv[s3];
        uint2 u0 = xb2[(size_t)s0 * 32 + l32];
        uint2 u1 = xb2[(size_t)s1 * 32 + l32];
        uint2 u2 = xb2[(size_t)s2 * 32 + l32];
        uint2 u3 = xb2[(size_t)s3 * 32 + l32];
        a0 += w0 * bflo(u0.x) + w1 * bflo(u1.x) + w2 * bflo(u2.x) + w3 * bflo(u3.x);
        a1 += w0 * bfhi(u0.x) + w1 * bfhi(u1.x) + w2 * bfhi(u2.x) + w3 * bfhi(u3.x);
        a2 += w0 * bflo(u0.y) + w1 * bflo(u1.y) + w2 * bflo(u2.y) + w3 * bflo(u3.y);
        a3 += w0 * bfhi(u0.y) + w1 * bfhi(u1.y) + w2 * bfhi(u2.y) + w3 * bfhi(u3.y);
    }
    for (; e < e1; ++e) {
        int s = esrc[e];
        float w = dinv[s];
        uint2 u = xb2[(size_t)s * 32 + l32];
        a0 += w * bflo(u.x);
        a1 += w * bfhi(u.x);
        a2 += w * bflo(u.y);
        a3 += w * bfhi(u.y);
    }
    a0 *= di; a1 *= di; a2 *= di; a3 *= di;
    uint2 o;
    o.x = (unsigned int)f2bf(a0) | ((unsigned int)f2bf(a1) << 16);
    o.y = (unsigned int)f2bf(a2) | ((unsigned int)f2bf(a3) << 16);
    xagg2[(size_t)node * 32 + l32] = o;
}

// ---------------- GEMM1: h = bf16(relu(xagg @ W1 + b1)), MFMA 16x16x32 ----------------
__launch_bounds__(256)
__global__ void k_gemm1(const unsigned short* __restrict__ A,   // xagg bf16 [M][128]
                        const unsigned short* __restrict__ BT,  // W1T bf16 [256][128]
                        const float* __restrict__ bias,
                        unsigned short* __restrict__ H) {       // h bf16 [M][256]
    __shared__ __align__(16) unsigned short As[128][72];
    __shared__ __align__(16) unsigned short Bs[128][72];
    int tid = threadIdx.x;
    int row0 = blockIdx.x * 128, col0 = blockIdx.y * 128;
    int w = tid >> 6, lane = tid & 63;
    int wm = w & 1, wn = w >> 1;
    int quad = lane >> 4, l16 = lane & 15;
    f32x4 acc[4][4];
#pragma unroll
    for (int i = 0; i < 4; i++)
#pragma unroll
        for (int j = 0; j < 4; j++) acc[i][j] = (f32x4){0.f, 0.f, 0.f, 0.f};

    for (int kc = 0; kc < 2; ++kc) {
        int k0 = kc * 64;
        __syncthreads();
#pragma unroll
        for (int i = 0; i < 4; i++) {
            int flat = i * 256 + tid;
            int r = flat >> 3, ko = (flat & 7) * 8;
            int row = row0 + r;
            uint4 val = make_uint4(0, 0, 0, 0);
            if (row < N_NODES) val = *(const uint4*)(A + (size_t)row * F_IN + k0 + ko);
            *(uint4*)&As[r][ko] = val;
        }
#pragma unroll
        for (int i = 0; i < 4; i++) {
            int flat = i * 256 + tid;
            int n = flat >> 3, ko = (flat & 7) * 8;
            *(uint4*)&Bs[n][ko] = *(const uint4*)(BT + (size_t)(col0 + n) * F_IN + k0 + ko);
        }
        __syncthreads();
#pragma unroll
        for (int ks = 0; ks < 2; ks++) {
            int koff = ks * 32 + quad * 8;
            bf16x8 af[4], bf[4];
#pragma unroll
            for (int i = 0; i < 4; i++) af[i] = *(const bf16x8*)&As[wm * 64 + i * 16 + l16][koff];
#pragma unroll
            for (int j = 0; j < 4; j++) bf[j] = *(const bf16x8*)&Bs[wn * 64 + j * 16 + l16][koff];
#pragma unroll
            for (int i = 0; i < 4; i++)
#pragma unroll
                for (int j = 0; j < 4; j++)
                    acc[i][j] = __builtin_amdgcn_mfma_f32_16x16x32_bf16(af[i], bf[j], acc[i][j], 0, 0, 0);
        }
    }
#pragma unroll
    for (int j = 0; j < 4; j++) {
        int gcol = col0 + wn * 64 + j * 16 + l16;
        float bj = bias[gcol];
#pragma unroll
        for (int i = 0; i < 4; i++) {
            int gr0 = row0 + wm * 64 + i * 16 + quad * 4;
#pragma unroll
            for (int r = 0; r < 4; r++) {
                int grow = gr0 + r;
                if (grow < N_NODES) {
                    float val = fmaxf(acc[i][j][r] + bj, 0.0f);
                    H[(size_t)grow * F_HID + gcol] = f2bf(val);
                }
            }
        }
    }
}

// ---------------- GEMM2: h2b = bf16(h @ W2), [M][64] padded, MFMA ----------------
__launch_bounds__(256)
__global__ void k_gemm2(const unsigned short* __restrict__ A,   // h bf16 [M][256]
                        const unsigned short* __restrict__ BT,  // W2T bf16 [64][256]
                        unsigned short* __restrict__ C) {       // h2b bf16 [M][64]
    __shared__ __align__(16) unsigned short As[256][72];
    __shared__ __align__(16) unsigned short Bs[64][72];
    int tid = threadIdx.x;
    int row0 = blockIdx.x * 256;
    int w = tid >> 6, lane = tid & 63;
    int quad = lane >> 4, l16 = lane & 15;
    f32x4 acc[4][3];
#pragma unroll
    for (int i = 0; i < 4; i++)
#pragma unroll
        for (int j = 0; j < 3; j++) acc[i][j] = (f32x4){0.f, 0.f, 0.f, 0.f};

    for (int kc = 0; kc < 4; ++kc) {
        int k0 = kc * 64;
        __syncthreads();
#pragma unroll
        for (int i = 0; i < 8; i++) {
            int flat = i * 256 + tid;
            int r = flat >> 3, ko = (flat & 7) * 8;
            int row = row0 + r;
            uint4 val = make_uint4(0, 0, 0, 0);
            if (row < N_NODES) val = *(const uint4*)(A + (size_t)row * F_HID + k0 + ko);
            *(uint4*)&As[r][ko] = val;
        }
#pragma unroll
        for (int i = 0; i < 2; i++) {
            int f2 = i * 256 + tid;
            int n = f2 >> 3, ko = (f2 & 7) * 8;
            *(uint4*)&Bs[n][ko] = *(const uint4*)(BT + (size_t)n * F_HID + k0 + ko);
        }
        __syncthreads();
#pragma unroll
        for (int ks = 0; ks < 2; ks++) {
            int koff = ks * 32 + quad * 8;
            bf16x8 af[4], bf[3];
#pragma unroll
            for (int i = 0; i < 4; i++) af[i] = *(const bf16x8*)&As[w * 64 + i * 16 + l16][koff];
#pragma unroll
            for (int j = 0; j < 3; j++) bf[j] = *(const bf16x8*)&Bs[j * 16 + l16][koff];
#pragma unroll
            for (int i = 0; i < 4; i++)
#pragma unroll
                for (int j = 0; j < 3; j++)
                    acc[i][j] = __builtin_amdgcn_mfma_f32_16x16x32_bf16(af[i], bf[j], acc[i][j], 0, 0, 0);
        }
    }
#pragma unroll
    for (int j = 0; j < 3; j++) {
        int col = j * 16 + l16;
        if (col < F_OUT) {
#pragma unroll
            for (int i = 0; i < 4; i++) {
                int gr0 = row0 + w * 64 + i * 16 + quad * 4;
#pragma unroll
                for (int r = 0; r < 4; r++) {
                    int grow = gr0 + r;
                    if (grow < N_NODES) C[(size_t)grow * 64 + col] = f2bf(acc[i][j][r]);
                }
            }
        }
    }
}

// ---------------- layer 2 aggregation + bias + log_softmax ----------------
__global__ void k_agg2(const unsigned int* __restrict__ h2v,  // bf16 [M][64] as uint [M][32]
                       const float* __restrict__ dinv,
                       const int* __restrict__ rowstart, const int* __restrict__ esrc,
                       const float* __restrict__ b2, float* __restrict__ out) {
    int node = blockIdx.x * 8 + (threadIdx.x >> 5);
    int l32 = threadIdx.x & 31;
    bool act = l32 < 20;
    float di = dinv[node];
    float acc0 = 0.0f, acc1 = 0.0f;
    if (act) {
        unsigned int u = h2v[(size_t)node * 32 + l32];
        acc0 = di * bflo(u);
        acc1 = di * bfhi(u);
    }
    int e0 = rowstart[node], e1 = rowstart[node + 1];
    int e = e0;
    for (; e + 3 < e1; e += 4) {
        int s0 = esrc[e], s1 = esrc[e + 1], s2 = esrc[e + 2], s3 = esrc[e + 3];
        float w0 = dinv[s0], w1 = dinv[s1], w2 = dinv[s2], w3 = dinv[s3];
        if (act) {
            unsigned int u0 = h2v[(size_t)s0 * 32 + l32];
            unsigned int u1 = h2v[(size_t)s1 * 32 + l32];
            unsigned int u2 = h2v[(size_t)s2 * 32 + l32];
            unsigned int u3 = h2v[(size_t)s3 * 32 + l32];
            acc0 += w0 * bflo(u0) + w1 * bflo(u1) + w2 * bflo(u2) + w3 * bflo(u3);
            acc1 += w0 * bfhi(u0) + w1 * bfhi(u1) + w2 * bfhi(u2) + w3 * bfhi(u3);
        }
    }
    for (; e < e1; ++e) {
        int s = esrc[e];
        float w = dinv[s];
        if (act) {
            unsigned int u = h2v[(size_t)s * 32 + l32];
            acc0 += w * bflo(u);
            acc1 += w * bfhi(u);
        }
    }
    float val0 = -3.0e38f, val1 = -3.0e38f;
    if (act) {
        float2 bb = ((const float2*)b2)[l32];
        val0 = di * acc0 + bb.x;
        val1 = di * acc1 + bb.y;
    }
    float m = fmaxf(val0, val1);
#pragma unroll
    for (int off = 16; off; off >>= 1) m = fmaxf(m, __shfl_xor(m, off));
    float ex = act ? (__expf(val0 - m) + __expf(val1 - m)) : 0.0f;
    float ssum = ex;
#pragma unroll
    for (int off = 16; off; off >>= 1) ssum += __shfl_xor(ssum, off);
    float logs = logf(ssum);
    if (act) {
        float2 o = make_float2(val0 - m - logs, val1 - m - logs);
        ((float2*)(out + (size_t)node * F_OUT))[l32] = o;
    }
}

// ---------------- launch ----------------

extern "C" void kernel_launch(void* const* d_in, const int* in_sizes, int n_in,
                              void* d_out, int out_size, void* d_ws, size_t ws_size,
                              hipStream_t stream) {
    const float* x  = (const float*)d_in[0];
    const int* edge = (const int*)d_in[1];
    const float* W1 = (const float*)d_in[2];
    const float* b1 = (const float*)d_in[3];
    const float* W2 = (const float*)d_in[4];
    const float* b2 = (const float*)d_in[5];
    float* out = (float*)d_out;
    const int* src = edge;
    const int* dst = edge + N_EDGES;

    char* ws = (char*)d_ws;
    size_t off = 0;
    auto alloc = [&](size_t bytes) -> void* {
        void* p = ws + off;
        off = (off + bytes + 255) & ~(size_t)255;
        return p;
    };
    float* dinv   = (float*)alloc((size_t)N_NODES * 4);
    int* cnt      = (int*)alloc((size_t)N_NODES * 4);
    int* slot     = (int*)alloc((size_t)N_EDGES * 4);  // edge slot within dst bucket
    int* rowstart = (int*)alloc((size_t)(N_NODES + 1) * 4);
    int* bsum     = (int*)alloc(128 * 4);
    int* boff     = (int*)alloc(128 * 4);
    int* esrc     = (int*)alloc((size_t)N_EDGES * 4);
    unsigned int* xb     = (unsigned int*)alloc((size_t)N_NODES * F_IN * 2);  // bf16 25.6 MB
    unsigned int* xagg   = (unsigned int*)alloc((size_t)N_NODES * F_IN * 2);  // bf16 25.6 MB
    unsigned short* W1T  = (unsigned short*)alloc((size_t)F_HID * F_IN * 2);
    unsigned short* W2T  = (unsigned short*)alloc((size_t)64 * F_HID * 2);
    unsigned short* h    = (unsigned short*)alloc((size_t)N_NODES * F_HID * 2);  // 51.2 MB
    unsigned short* h2b  = (unsigned short*)alloc((size_t)N_NODES * 64 * 2);     // 12.8 MB
    (void)ws_size; (void)in_sizes; (void)n_in; (void)out_size;

    int nb = (N_NODES + 1023) / 1024;  // 98

    hipMemsetAsync(cnt, 0, (size_t)N_NODES * 4, stream);
    hipLaunchKernelGGL(k_count2, dim3((N_EDGES + 255) / 256), dim3(256), 0, stream, dst, cnt, slot);
    hipLaunchKernelGGL(k_scan_partial, dim3(nb), dim3(256), 0, stream, cnt, rowstart, dinv, bsum);
    hipLaunchKernelGGL(k_scan_blocks, dim3(1), dim3(128), 0, stream, bsum, boff, rowstart, nb);
    hipLaunchKernelGGL(k_add_off, dim3(nb), dim3(256), 0, stream, rowstart, boff);
    hipLaunchKernelGGL(k_fill2, dim3(1024), dim3(256), 0, stream, src, dst, slot, rowstart, esrc);
    hipLaunchKernelGGL(k_cast_x, dim3(N_NODES * F_IN / 4 / 256), dim3(256), 0, stream, x, (uint2*)xb);
    hipLaunchKernelGGL(k_prep_w, dim3(192), dim3(256), 0, stream, W1, W2, W1T, W2T);
    hipLaunchKernelGGL(k_agg1, dim3(N_NODES / 8), dim3(256), 0, stream,
                       (const uint2*)xb, dinv, rowstart, esrc, (uint2*)xagg);
    hipLaunchKernelGGL(k_gemm1, dim3(782, 2), dim3(256), 0, stream,
                       (const unsigned short*)xagg, W1T, b1, h);
    hipLaunchKernelGGL(k_gemm2, dim3(391), dim3(256), 0, stream, h, W2T, h2b);
    hipLaunchKernelGGL(k_agg2, dim3(N_NODES / 8), dim3(256), 0, stream,
                       (const unsigned int*)h2b, dinv, rowstart, esrc, b2, out);
}

// Round 5
// 321.149 us; speedup vs baseline: 1.8496x; 1.0350x over previous
//
#include <hip/hip_runtime.h>

#define N_NODES 100000
#define N_EDGES 1000000
#define F_IN 128
#define F_HID 256
#define F_OUT 40
#define GROUP_NODES 12500  // N_NODES / 8 XCD-partition for the CSR fill

typedef __attribute__((ext_vector_type(8))) short bf16x8;
typedef __attribute__((ext_vector_type(4))) float f32x4;

__device__ inline unsigned short f2bf(float f) {
    unsigned int u = __float_as_uint(f);
    return (unsigned short)((u + 0x7fffu + ((u >> 16) & 1u)) >> 16);
}
__device__ inline float bflo(unsigned int u) { return __uint_as_float(u << 16); }
__device__ inline float bfhi(unsigned int u) { return __uint_as_float(u & 0xffff0000u); }
__device__ inline unsigned int pack2(float a, float b) {
    return (unsigned int)f2bf(a) | ((unsigned int)f2bf(b) << 16);
}

// ---------------- CSR build ----------------

// count + record each edge's slot within its dst bucket (atomic return value)
__global__ void k_count2(const int* __restrict__ dst, int* __restrict__ cnt,
                         int* __restrict__ slot) {
    int e = blockIdx.x * 256 + threadIdx.x;
    if (e < N_EDGES) slot[e] = atomicAdd(&cnt[dst[e]], 1);
}

__global__ void k_scan_partial(const int* __restrict__ cnt, int* __restrict__ rowstart,
                               float* __restrict__ dinv, int* __restrict__ bsum) {
    __shared__ int wsum[4];
    int tid = threadIdx.x;
    int base = blockIdx.x * 1024 + tid * 4;
    int v[4];
#pragma unroll
    for (int j = 0; j < 4; j++) {
        int i = base + j;
        v[j] = (i < N_NODES) ? cnt[i] : 0;
        if (i < N_NODES) dinv[i] = rsqrtf((float)v[j] + 1.0f);  // +1 self-loop
    }
    int t = v[0] + v[1] + v[2] + v[3];
    int lane = tid & 63, wave = tid >> 6;
    int incl = t;
#pragma unroll
    for (int off = 1; off < 64; off <<= 1) {
        int u = __shfl_up(incl, off);
        if (lane >= off) incl += u;
    }
    if (lane == 63) wsum[wave] = incl;
    __syncthreads();
    int woff = 0;
    for (int w = 0; w < wave; w++) woff += wsum[w];
    int run = woff + incl - t;
#pragma unroll
    for (int j = 0; j < 4; j++) {
        int i = base + j;
        if (i < N_NODES) rowstart[i] = run;
        run += v[j];
    }
    if (tid == 255) bsum[blockIdx.x] = woff + incl;
}

__global__ void k_scan_blocks(const int* __restrict__ bsum, int* __restrict__ boff,
                              int* __restrict__ rowstart, int nb) {
    __shared__ int wtot[2];
    int tid = threadIdx.x;
    int v = (tid < nb) ? bsum[tid] : 0;
    int lane = tid & 63, wave = tid >> 6;
    int incl = v;
#pragma unroll
    for (int off = 1; off < 64; off <<= 1) {
        int u = __shfl_up(incl, off);
        if (lane >= off) incl += u;
    }
    if (lane == 63) wtot[wave] = incl;
    __syncthreads();
    int excl = incl - v + (wave ? wtot[0] : 0);
    if (tid < nb) boff[tid] = excl;
    if (tid == 0) rowstart[N_NODES] = N_EDGES;
}

__global__ void k_add_off(int* __restrict__ rowstart, const int* __restrict__ boff) {
    int base = blockIdx.x * 1024 + threadIdx.x * 4;
    int off = boff[blockIdx.x];
#pragma unroll
    for (int j = 0; j < 4; j++) {
        int i = base + j;
        if (i < N_NODES) rowstart[i] += off;
    }
}

// XCD-partitioned, atomic-free fill
__global__ void k_fill2(const int* __restrict__ src, const int* __restrict__ dst,
                        const int* __restrict__ slot, const int* __restrict__ rowstart,
                        int* __restrict__ esrc) {
    int g = blockIdx.x & 7;
    int bg = blockIdx.x >> 3;
    int nbg = gridDim.x >> 3;
    int lo = g * GROUP_NODES;
    int hi = lo + GROUP_NODES;
    for (int base = (bg * 256 + threadIdx.x) * 4; base < N_EDGES; base += nbg * 1024) {
        int4 d4 = *(const int4*)(dst + base);
#pragma unroll
        for (int j = 0; j < 4; j++) {
            int d = (&d4.x)[j];
            if (d >= lo && d < hi) {
                int s = src[base + j];
                int sl = slot[base + j];
                esrc[rowstart[d] + sl] = s;
            }
        }
    }
}

// ---------------- casts / weight prep ----------------

__global__ void k_cast_x(const float* __restrict__ x, uint2* __restrict__ xb) {
    int i = blockIdx.x * 256 + threadIdx.x;
    float4 v = ((const float4*)x)[i];
    xb[i] = make_uint2(pack2(v.x, v.y), pack2(v.z, v.w));
}

// W1T[n][k] = bf16(W1[k][n]) [256][128];  W2T[n][k] = bf16(W2[k][n]) [64][256]
__global__ void k_prep_w(const float* __restrict__ W1, const float* __restrict__ W2,
                         unsigned short* __restrict__ W1T, unsigned short* __restrict__ W2T) {
    int i = blockIdx.x * 256 + threadIdx.x;
    if (i < 32768) {
        int n = i >> 7, k = i & 127;
        W1T[i] = f2bf(W1[k * F_HID + n]);
    } else {
        int j = i - 32768;
        int n = j >> 8, k = j & 255;
        W2T[j] = (n < F_OUT) ? f2bf(W2[k * F_OUT + n]) : (unsigned short)0;
    }
}

// ---------------- layer 1 aggregation: 32-lane group per node, 2 nodes/wave ----------------
__global__ void k_agg1(const uint2* __restrict__ xb2, const float* __restrict__ dinv,
                       const int* __restrict__ rowstart, const int* __restrict__ esrc,
                       uint2* __restrict__ xagg2) {
    int node = blockIdx.x * 8 + (threadIdx.x >> 5);
    int l32 = threadIdx.x & 31;
    float di = dinv[node];
    uint2 v = xb2[(size_t)node * 32 + l32];
    float a0 = di * bflo(v.x), a1 = di * bfhi(v.x);
    float a2 = di * bflo(v.y), a3 = di * bfhi(v.y);
    int e0 = rowstart[node], e1 = rowstart[node + 1];
    int e = e0;
    for (; e + 3 < e1; e += 4) {
        int s0 = esrc[e], s1 = esrc[e + 1], s2 = esrc[e + 2], s3 = esrc[e + 3];
        float w0 = dinv[s0], w1 = dinv[s1], w2 = dinv[s2], w3 = dinv[s3];
        uint2 u0 = xb2[(size_t)s0 * 32 + l32];
        uint2 u1 = xb2[(size_t)s1 * 32 + l32];
        uint2 u2 = xb2[(size_t)s2 * 32 + l32];
        uint2 u3 = xb2[(size_t)s3 * 32 + l32];
        a0 += w0 * bflo(u0.x) + w1 * bflo(u1.x) + w2 * bflo(u2.x) + w3 * bflo(u3.x);
        a1 += w0 * bfhi(u0.x) + w1 * bfhi(u1.x) + w2 * bfhi(u2.x) + w3 * bfhi(u3.x);
        a2 += w0 * bflo(u0.y) + w1 * bflo(u1.y) + w2 * bflo(u2.y) + w3 * bflo(u3.y);
        a3 += w0 * bfhi(u0.y) + w1 * bfhi(u1.y) + w2 * bfhi(u2.y) + w3 * bfhi(u3.y);
    }
    for (; e < e1; ++e) {
        int s = esrc[e];
        float w = dinv[s];
        uint2 u = xb2[(size_t)s * 32 + l32];
        a0 += w * bflo(u.x);
        a1 += w * bfhi(u.x);
        a2 += w * bflo(u.y);
        a3 += w * bfhi(u.y);
    }
    a0 *= di; a1 *= di; a2 *= di; a3 *= di;
    xagg2[(size_t)node * 32 + l32] = make_uint2(pack2(a0, a1), pack2(a2, a3));
}

// ---------------- fused GEMM: h2b = bf16( relu(xagg@W1+b1) @ W2 ) ----------------
// One block = 64 node rows. Stage 1 holds h tile in LDS only (never HBM).
// Both stages swap MFMA operands (W as A-operand) so each lane's 4 acc regs
// are 4 CONSECUTIVE output columns -> 8 B packed stores, no write inflation.
__launch_bounds__(256)
__global__ void k_fused_gemm(const unsigned short* __restrict__ A,    // xagg bf16 [M][128]
                             const unsigned short* __restrict__ W1T,  // [256][128]
                             const unsigned short* __restrict__ W2T,  // [64][256]
                             const float* __restrict__ b1,
                             unsigned short* __restrict__ h2b) {      // bf16 [M][64]
    __shared__ __align__(16) unsigned short Hs[64][264];  // 33.8 KB
    int tid = threadIdx.x;
    int w = tid >> 6, lane = tid & 63;
    int quad = lane >> 4, l16 = lane & 15;
    int row0 = blockIdx.x * 64;
    int mhalf = w >> 1;  // which 128-col half of W1 this wave computes
    int nhalf = w & 1;   // which 32-node half this wave computes

    // ---- stage 1: h[64][256] = relu(xagg @ W1 + b1) -> LDS ----
    f32x4 acc[2][8];
#pragma unroll
    for (int nt = 0; nt < 2; nt++)
#pragma unroll
        for (int mt = 0; mt < 8; mt++) acc[nt][mt] = (f32x4){0.f, 0.f, 0.f, 0.f};

#pragma unroll
    for (int kc = 0; kc < 4; ++kc) {
        int k0 = kc * 32;
        bf16x8 bf[2], af[8];
#pragma unroll
        for (int nt = 0; nt < 2; nt++) {
            int row = row0 + nhalf * 32 + nt * 16 + l16;
            row = row < N_NODES ? row : N_NODES - 1;
            bf[nt] = *(const bf16x8*)(A + (size_t)row * F_IN + k0 + quad * 8);
        }
#pragma unroll
        for (int mt = 0; mt < 8; mt++)
            af[mt] = *(const bf16x8*)(W1T + (size_t)(mhalf * 128 + mt * 16 + l16) * F_IN + k0 + quad * 8);
#pragma unroll
        for (int nt = 0; nt < 2; nt++)
#pragma unroll
            for (int mt = 0; mt < 8; mt++)
                acc[nt][mt] = __builtin_amdgcn_mfma_f32_16x16x32_bf16(af[mt], bf[nt], acc[nt][mt], 0, 0, 0);
    }
    // epilogue 1: bias + relu, pack 4 consecutive cols -> ds_write_b64
#pragma unroll
    for (int mt = 0; mt < 8; mt++) {
        int colbase = mhalf * 128 + mt * 16 + quad * 4;
        float4 bb = *(const float4*)(b1 + colbase);
#pragma unroll
        for (int nt = 0; nt < 2; nt++) {
            int nrow = nhalf * 32 + nt * 16 + l16;
            float v0 = fmaxf(acc[nt][mt][0] + bb.x, 0.f);
            float v1 = fmaxf(acc[nt][mt][1] + bb.y, 0.f);
            float v2 = fmaxf(acc[nt][mt][2] + bb.z, 0.f);
            float v3 = fmaxf(acc[nt][mt][3] + bb.w, 0.f);
            *(uint2*)&Hs[nrow][colbase] = make_uint2(pack2(v0, v1), pack2(v2, v3));
        }
    }
    __syncthreads();

    // ---- stage 2: out[64][64] = h @ W2 ----
    f32x4 acc2[4];
#pragma unroll
    for (int mt = 0; mt < 4; mt++) acc2[mt] = (f32x4){0.f, 0.f, 0.f, 0.f};
#pragma unroll
    for (int kc = 0; kc < 8; ++kc) {
        int k0 = kc * 32;
        bf16x8 hf = *(const bf16x8*)&Hs[w * 16 + l16][k0 + quad * 8];
        bf16x8 wf[4];
#pragma unroll
        for (int mt = 0; mt < 4; mt++)
            wf[mt] = *(const bf16x8*)(W2T + (size_t)(mt * 16 + l16) * F_HID + k0 + quad * 8);
#pragma unroll
        for (int mt = 0; mt < 4; mt++)
            acc2[mt] = __builtin_amdgcn_mfma_f32_16x16x32_bf16(wf[mt], hf, acc2[mt], 0, 0, 0);
    }
    int grow = row0 + w * 16 + l16;
    if (grow < N_NODES) {
#pragma unroll
        for (int mt = 0; mt < 4; mt++) {
            uint2 o = make_uint2(pack2(acc2[mt][0], acc2[mt][1]), pack2(acc2[mt][2], acc2[mt][3]));
            *(uint2*)(h2b + (size_t)grow * 64 + mt * 16 + quad * 4) = o;
        }
    }
}

// ---------------- layer 2 aggregation + bias + log_softmax ----------------
__global__ void k_agg2(const unsigned int* __restrict__ h2v,  // bf16 [M][64] as uint [M][32]
                       const float* __restrict__ dinv,
                       const int* __restrict__ rowstart, const int* __restrict__ esrc,
                       const float* __restrict__ b2, float* __restrict__ out) {
    int node = blockIdx.x * 8 + (threadIdx.x >> 5);
    int l32 = threadIdx.x & 31;
    bool act = l32 < 20;
    float di = dinv[node];
    float acc0 = 0.0f, acc1 = 0.0f;
    if (act) {
        unsigned int u = h2v[(size_t)node * 32 + l32];
        acc0 = di * bflo(u);
        acc1 = di * bfhi(u);
    }
    int e0 = rowstart[node], e1 = rowstart[node + 1];
    int e = e0;
    for (; e + 3 < e1; e += 4) {
        int s0 = esrc[e], s1 = esrc[e + 1], s2 = esrc[e + 2], s3 = esrc[e + 3];
        float w0 = dinv[s0], w1 = dinv[s1], w2 = dinv[s2], w3 = dinv[s3];
        if (act) {
            unsigned int u0 = h2v[(size_t)s0 * 32 + l32];
            unsigned int u1 = h2v[(size_t)s1 * 32 + l32];
            unsigned int u2 = h2v[(size_t)s2 * 32 + l32];
            unsigned int u3 = h2v[(size_t)s3 * 32 + l32];
            acc0 += w0 * bflo(u0) + w1 * bflo(u1) + w2 * bflo(u2) + w3 * bflo(u3);
            acc1 += w0 * bfhi(u0) + w1 * bfhi(u1) + w2 * bfhi(u2) + w3 * bfhi(u3);
        }
    }
    for (; e < e1; ++e) {
        int s = esrc[e];
        float w = dinv[s];
        if (act) {
            unsigned int u = h2v[(size_t)s * 32 + l32];
            acc0 += w * bflo(u);
            acc1 += w * bfhi(u);
        }
    }
    float val0 = -3.0e38f, val1 = -3.0e38f;
    if (act) {
        float2 bb = ((const float2*)b2)[l32];
        val0 = di * acc0 + bb.x;
        val1 = di * acc1 + bb.y;
    }
    float m = fmaxf(val0, val1);
#pragma unroll
    for (int off = 16; off; off >>= 1) m = fmaxf(m, __shfl_xor(m, off));
    float ex = act ? (__expf(val0 - m) + __expf(val1 - m)) : 0.0f;
    float ssum = ex;
#pragma unroll
    for (int off = 16; off; off >>= 1) ssum += __shfl_xor(ssum, off);
    float logs = logf(ssum);
    if (act) {
        float2 o = make_float2(val0 - m - logs, val1 - m - logs);
        ((float2*)(out + (size_t)node * F_OUT))[l32] = o;
    }
}

// ---------------- launch ----------------

extern "C" void kernel_launch(void* const* d_in, const int* in_sizes, int n_in,
                              void* d_out, int out_size, void* d_ws, size_t ws_size,
                              hipStream_t stream) {
    const float* x  = (const float*)d_in[0];
    const int* edge = (const int*)d_in[1];
    const float* W1 = (const float*)d_in[2];
    const float* b1 = (const float*)d_in[3];
    const float* W2 = (const float*)d_in[4];
    const float* b2 = (const float*)d_in[5];
    float* out = (float*)d_out;
    const int* src = edge;
    const int* dst = edge + N_EDGES;

    char* ws = (char*)d_ws;
    size_t off = 0;
    auto alloc = [&](size_t bytes) -> void* {
        void* p = ws + off;
        off = (off + bytes + 255) & ~(size_t)255;
        return p;
    };
    float* dinv   = (float*)alloc((size_t)N_NODES * 4);
    int* cnt      = (int*)alloc((size_t)N_NODES * 4);
    int* slot     = (int*)alloc((size_t)N_EDGES * 4);
    int* rowstart = (int*)alloc((size_t)(N_NODES + 1) * 4);
    int* bsum     = (int*)alloc(128 * 4);
    int* boff     = (int*)alloc(128 * 4);
    int* esrc     = (int*)alloc((size_t)N_EDGES * 4);
    unsigned int* xb     = (unsigned int*)alloc((size_t)N_NODES * F_IN * 2);  // bf16 25.6 MB
    unsigned int* xagg   = (unsigned int*)alloc((size_t)N_NODES * F_IN * 2);  // bf16 25.6 MB
    unsigned short* W1T  = (unsigned short*)alloc((size_t)F_HID * F_IN * 2);
    unsigned short* W2T  = (unsigned short*)alloc((size_t)64 * F_HID * 2);
    unsigned short* h2b  = (unsigned short*)alloc((size_t)N_NODES * 64 * 2);  // 12.8 MB
    (void)ws_size; (void)in_sizes; (void)n_in; (void)out_size;

    int nb = (N_NODES + 1023) / 1024;  // 98

    hipMemsetAsync(cnt, 0, (size_t)N_NODES * 4, stream);
    hipLaunchKernelGGL(k_count2, dim3((N_EDGES + 255) / 256), dim3(256), 0, stream, dst, cnt, slot);
    hipLaunchKernelGGL(k_scan_partial, dim3(nb), dim3(256), 0, stream, cnt, rowstart, dinv, bsum);
    hipLaunchKernelGGL(k_scan_blocks, dim3(1), dim3(128), 0, stream, bsum, boff, rowstart, nb);
    hipLaunchKernelGGL(k_add_off, dim3(nb), dim3(256), 0, stream, rowstart, boff);
    hipLaunchKernelGGL(k_fill2, dim3(1024), dim3(256), 0, stream, src, dst, slot, rowstart, esrc);
    hipLaunchKernelGGL(k_cast_x, dim3(N_NODES * F_IN / 4 / 256), dim3(256), 0, stream, x, (uint2*)xb);
    hipLaunchKernelGGL(k_prep_w, dim3(192), dim3(256), 0, stream, W1, W2, W1T, W2T);
    hipLaunchKernelGGL(k_agg1, dim3(N_NODES / 8), dim3(256), 0, stream,
                       (const uint2*)xb, dinv, rowstart, esrc, (uint2*)xagg);
    hipLaunchKernelGGL(k_fused_gemm, dim3((N_NODES + 63) / 64), dim3(256), 0, stream,
                       (const unsigned short*)xagg, W1T, W2T, b1, h2b);
    hipLaunchKernelGGL(k_agg2, dim3(N_NODES / 8), dim3(256), 0, stream,
                       (const unsigned int*)h2b, dinv, rowstart, esrc, b2, out);
}

// Round 6
// 292.513 us; speedup vs baseline: 2.0307x; 1.0979x over previous
//
#include <hip/hip_runtime.h>

#define N_NODES 100000
#define N_EDGES 1000000
#define F_IN 128
#define F_HID 256
#define F_OUT 40
#define GROUP_NODES 12500  // N_NODES / 8 XCD-partition for the CSR fill
#define N_TILES 1563       // ceil(N_NODES / 64)

typedef __attribute__((ext_vector_type(8))) short bf16x8;
typedef __attribute__((ext_vector_type(4))) float f32x4;

__device__ inline unsigned short f2bf(float f) {
    unsigned int u = __float_as_uint(f);
    return (unsigned short)((u + 0x7fffu + ((u >> 16) & 1u)) >> 16);
}
__device__ inline float bflo(unsigned int u) { return __uint_as_float(u << 16); }
__device__ inline float bfhi(unsigned int u) { return __uint_as_float(u & 0xffff0000u); }
__device__ inline unsigned int pack2(float a, float b) {
    return (unsigned int)f2bf(a) | ((unsigned int)f2bf(b) << 16);
}

// ---------------- CSR build ----------------

__global__ void k_count2(const int* __restrict__ dst, int* __restrict__ cnt,
                         int* __restrict__ slot) {
    int e = blockIdx.x * 256 + threadIdx.x;
    if (e < N_EDGES) slot[e] = atomicAdd(&cnt[dst[e]], 1);
}

__global__ void k_scan_partial(const int* __restrict__ cnt, int* __restrict__ rowstart,
                               float* __restrict__ dinv, int* __restrict__ bsum) {
    __shared__ int wsum[4];
    int tid = threadIdx.x;
    int base = blockIdx.x * 1024 + tid * 4;
    int v[4];
#pragma unroll
    for (int j = 0; j < 4; j++) {
        int i = base + j;
        v[j] = (i < N_NODES) ? cnt[i] : 0;
        if (i < N_NODES) dinv[i] = rsqrtf((float)v[j] + 1.0f);  // +1 self-loop
    }
    int t = v[0] + v[1] + v[2] + v[3];
    int lane = tid & 63, wave = tid >> 6;
    int incl = t;
#pragma unroll
    for (int off = 1; off < 64; off <<= 1) {
        int u = __shfl_up(incl, off);
        if (lane >= off) incl += u;
    }
    if (lane == 63) wsum[wave] = incl;
    __syncthreads();
    int woff = 0;
    for (int w = 0; w < wave; w++) woff += wsum[w];
    int run = woff + incl - t;
#pragma unroll
    for (int j = 0; j < 4; j++) {
        int i = base + j;
        if (i < N_NODES) rowstart[i] = run;
        run += v[j];
    }
    if (tid == 255) bsum[blockIdx.x] = woff + incl;
}

__global__ void k_scan_blocks(const int* __restrict__ bsum, int* __restrict__ boff,
                              int* __restrict__ rowstart, int nb) {
    __shared__ int wtot[2];
    int tid = threadIdx.x;
    int v = (tid < nb) ? bsum[tid] : 0;
    int lane = tid & 63, wave = tid >> 6;
    int incl = v;
#pragma unroll
    for (int off = 1; off < 64; off <<= 1) {
        int u = __shfl_up(incl, off);
        if (lane >= off) incl += u;
    }
    if (lane == 63) wtot[wave] = incl;
    __syncthreads();
    int excl = incl - v + (wave ? wtot[0] : 0);
    if (tid < nb) boff[tid] = excl;
    if (tid == 0) rowstart[N_NODES] = N_EDGES;
}

__global__ void k_add_off(int* __restrict__ rowstart, const int* __restrict__ boff) {
    int base = blockIdx.x * 1024 + threadIdx.x * 4;
    int off = boff[blockIdx.x];
#pragma unroll
    for (int j = 0; j < 4; j++) {
        int i = base + j;
        if (i < N_NODES) rowstart[i] += off;
    }
}

__global__ void k_fill2(const int* __restrict__ src, const int* __restrict__ dst,
                        const int* __restrict__ slot, const int* __restrict__ rowstart,
                        int* __restrict__ esrc) {
    int g = blockIdx.x & 7;
    int bg = blockIdx.x >> 3;
    int nbg = gridDim.x >> 3;
    int lo = g * GROUP_NODES;
    int hi = lo + GROUP_NODES;
    for (int base = (bg * 256 + threadIdx.x) * 4; base < N_EDGES; base += nbg * 1024) {
        int4 d4 = *(const int4*)(dst + base);
#pragma unroll
        for (int j = 0; j < 4; j++) {
            int d = (&d4.x)[j];
            if (d >= lo && d < hi) {
                int s = src[base + j];
                int sl = slot[base + j];
                esrc[rowstart[d] + sl] = s;
            }
        }
    }
}

// ---------------- casts / weight prep ----------------

__global__ void k_cast_x(const float* __restrict__ x, uint2* __restrict__ xb) {
    int i = blockIdx.x * 256 + threadIdx.x;
    float4 v = ((const float4*)x)[i];
    xb[i] = make_uint2(pack2(v.x, v.y), pack2(v.z, v.w));
}

// MFMA-fragment-order weights: one fragment = 64 lanes x 8 bf16, lane-contiguous.
// W1F flat = ((mhalf*4+kc)*8 + mt)*512 + lane*8 + j ; element (n,k):
//   n = mhalf*128 + mt*16 + l16, k = kc*32 + quad*8 + j, lane = quad*16+l16
// W2F flat = (kc*4 + mt)*512 + lane*8 + j ; n = mt*16+l16 (0 for n>=40), k = kc*32+quad*8+j
__global__ void k_prep_w(const float* __restrict__ W1, const float* __restrict__ W2,
                         unsigned short* __restrict__ W1F, unsigned short* __restrict__ W2F) {
    int i = blockIdx.x * 256 + threadIdx.x;  // 32768 + 16384 = 49152
    if (i < 32768) {
        int j = i & 7, lane = (i >> 3) & 63, mt = (i >> 9) & 7, kc = (i >> 12) & 3, mhalf = i >> 14;
        int l16 = lane & 15, quad = lane >> 4;
        int n = mhalf * 128 + mt * 16 + l16;
        int k = kc * 32 + quad * 8 + j;
        W1F[i] = f2bf(W1[k * F_HID + n]);
    } else {
        int i2 = i - 32768;
        int j = i2 & 7, lane = (i2 >> 3) & 63, mt = (i2 >> 9) & 3, kc = i2 >> 11;
        int l16 = lane & 15, quad = lane >> 4;
        int n = mt * 16 + l16;
        int k = kc * 32 + quad * 8 + j;
        W2F[i2] = (n < F_OUT) ? f2bf(W2[k * F_OUT + n]) : (unsigned short)0;
    }
}

// ---------------- layer 1 aggregation -> fragment-order xaggF ----------------
// One block owns one 64-node tile (8 node-groups x 8 iters) so all of a tile's
// fragment-scattered 8 B writes come from one block/XCD (no partial-line ping-pong).
// xaggF tile flat = (kc*4 + nhalf*2 + nt)*512 + (quad*16 + l16)*8 + j
//   for element (row_local, k): nhalf=row_local>>5, nt=(row_local>>4)&1, l16=row_local&15,
//   kc=k>>5, quad=(k>>3)&3, j=k&7.
__global__ void k_agg1(const uint2* __restrict__ xb2, const float* __restrict__ dinv,
                       const int* __restrict__ rowstart, const int* __restrict__ esrc,
                       unsigned short* __restrict__ xaggF) {
    int tile = blockIdx.x;
    int group = threadIdx.x >> 5;
    int l32 = threadIdx.x & 31;
    // lane's 4 feats are k = 4*l32 .. 4*l32+3 -> same fragment, j-base (l32&1)*4
    int kc = l32 >> 3;
    int quad = (l32 >> 1) & 3;
    int jb = (l32 & 1) * 4;
    unsigned short* tbase = xaggF + (size_t)tile * 8192;
    for (int it = 0; it < 8; ++it) {
        int row_local = it * 8 + group;
        int node = tile * 64 + row_local;
        if (node >= N_NODES) break;
        float di = dinv[node];
        uint2 v = xb2[(size_t)node * 32 + l32];
        float a0 = di * bflo(v.x), a1 = di * bfhi(v.x);
        float a2 = di * bflo(v.y), a3 = di * bfhi(v.y);
        int e0 = rowstart[node], e1 = rowstart[node + 1];
        int e = e0;
        for (; e + 3 < e1; e += 4) {
            int s0 = esrc[e], s1 = esrc[e + 1], s2 = esrc[e + 2], s3 = esrc[e + 3];
            float w0 = dinv[s0], w1 = dinv[s1], w2 = dinv[s2], w3 = dinv[s3];
            uint2 u0 = xb2[(size_t)s0 * 32 + l32];
            uint2 u1 = xb2[(size_t)s1 * 32 + l32];
            uint2 u2 = xb2[(size_t)s2 * 32 + l32];
            uint2 u3 = xb2[(size_t)s3 * 32 + l32];
            a0 += w0 * bflo(u0.x) + w1 * bflo(u1.x) + w2 * bflo(u2.x) + w3 * bflo(u3.x);
            a1 += w0 * bfhi(u0.x) + w1 * bfhi(u1.x) + w2 * bfhi(u2.x) + w3 * bfhi(u3.x);
            a2 += w0 * bflo(u0.y) + w1 * bflo(u1.y) + w2 * bflo(u2.y) + w3 * bflo(u3.y);
            a3 += w0 * bfhi(u0.y) + w1 * bfhi(u1.y) + w2 * bfhi(u2.y) + w3 * bfhi(u3.y);
        }
        for (; e < e1; ++e) {
            int s = esrc[e];
            float w = dinv[s];
            uint2 u = xb2[(size_t)s * 32 + l32];
            a0 += w * bflo(u.x);
            a1 += w * bfhi(u.x);
            a2 += w * bflo(u.y);
            a3 += w * bfhi(u.y);
        }
        a0 *= di; a1 *= di; a2 *= di; a3 *= di;
        int nhalf = row_local >> 5, nt = (row_local >> 4) & 1, l16 = row_local & 15;
        size_t off = (size_t)(kc * 4 + nhalf * 2 + nt) * 512 + (quad * 16 + l16) * 8 + jb;
        *(uint2*)(tbase + off) = make_uint2(pack2(a0, a1), pack2(a2, a3));
    }
}

// ---------------- fused GEMM: h2b = bf16( relu(xagg@W1+b1) @ W2 ) ----------------
// All GEMM operands in fragment order: every load is 64 lanes x 16 B contiguous.
__launch_bounds__(256)
__global__ void k_fused_gemm(const unsigned short* __restrict__ AF,   // xaggF frag-order
                             const unsigned short* __restrict__ W1F,  // frag-order 64 KB
                             const unsigned short* __restrict__ W2F,  // frag-order 32 KB
                             const float* __restrict__ b1,
                             unsigned short* __restrict__ h2b) {      // bf16 [M][64]
    __shared__ __align__(16) unsigned short Hs[64][264];  // 33.8 KB
    int tid = threadIdx.x;
    int w = tid >> 6, lane = tid & 63;
    int quad = lane >> 4, l16 = lane & 15;
    int row0 = blockIdx.x * 64;
    int mhalf = w >> 1;  // which 128-col half of W1 this wave computes
    int nhalf = w & 1;   // which 32-node half this wave computes
    const unsigned short* AT = AF + (size_t)blockIdx.x * 8192;

    // ---- stage 1: h[64][256] = relu(xagg @ W1 + b1) -> LDS ----
    f32x4 acc[2][8];
#pragma unroll
    for (int nt = 0; nt < 2; nt++)
#pragma unroll
        for (int mt = 0; mt < 8; mt++) acc[nt][mt] = (f32x4){0.f, 0.f, 0.f, 0.f};

#pragma unroll
    for (int kc = 0; kc < 4; ++kc) {
        bf16x8 bf[2], af[8];
#pragma unroll
        for (int nt = 0; nt < 2; nt++)
            bf[nt] = *(const bf16x8*)(AT + (size_t)(kc * 4 + nhalf * 2 + nt) * 512 + lane * 8);
#pragma unroll
        for (int mt = 0; mt < 8; mt++)
            af[mt] = *(const bf16x8*)(W1F + (size_t)((mhalf * 4 + kc) * 8 + mt) * 512 + lane * 8);
#pragma unroll
        for (int nt = 0; nt < 2; nt++)
#pragma unroll
            for (int mt = 0; mt < 8; mt++)
                acc[nt][mt] = __builtin_amdgcn_mfma_f32_16x16x32_bf16(af[mt], bf[nt], acc[nt][mt], 0, 0, 0);
    }
    // epilogue 1: bias + relu, pack 4 consecutive cols -> ds_write_b64
#pragma unroll
    for (int mt = 0; mt < 8; mt++) {
        int colbase = mhalf * 128 + mt * 16 + quad * 4;
        float4 bb = *(const float4*)(b1 + colbase);
#pragma unroll
        for (int nt = 0; nt < 2; nt++) {
            int nrow = nhalf * 32 + nt * 16 + l16;
            float v0 = fmaxf(acc[nt][mt][0] + bb.x, 0.f);
            float v1 = fmaxf(acc[nt][mt][1] + bb.y, 0.f);
            float v2 = fmaxf(acc[nt][mt][2] + bb.z, 0.f);
            float v3 = fmaxf(acc[nt][mt][3] + bb.w, 0.f);
            *(uint2*)&Hs[nrow][colbase] = make_uint2(pack2(v0, v1), pack2(v2, v3));
        }
    }
    __syncthreads();

    // ---- stage 2: out[64][64] = h @ W2 ----
    f32x4 acc2[4];
#pragma unroll
    for (int mt = 0; mt < 4; mt++) acc2[mt] = (f32x4){0.f, 0.f, 0.f, 0.f};
#pragma unroll
    for (int kc = 0; kc < 8; ++kc) {
        int k0 = kc * 32;
        bf16x8 hf = *(const bf16x8*)&Hs[w * 16 + l16][k0 + quad * 8];
        bf16x8 wf[4];
#pragma unroll
        for (int mt = 0; mt < 4; mt++)
            wf[mt] = *(const bf16x8*)(W2F + (size_t)(kc * 4 + mt) * 512 + lane * 8);
#pragma unroll
        for (int mt = 0; mt < 4; mt++)
            acc2[mt] = __builtin_amdgcn_mfma_f32_16x16x32_bf16(wf[mt], hf, acc2[mt], 0, 0, 0);
    }
    int grow = row0 + w * 16 + l16;
    if (grow < N_NODES) {
#pragma unroll
        for (int mt = 0; mt < 4; mt++) {
            uint2 o = make_uint2(pack2(acc2[mt][0], acc2[mt][1]), pack2(acc2[mt][2], acc2[mt][3]));
            *(uint2*)(h2b + (size_t)grow * 64 + mt * 16 + quad * 4) = o;
        }
    }
}

// ---------------- layer 2 aggregation + bias + log_softmax ----------------
__global__ void k_agg2(const unsigned int* __restrict__ h2v,  // bf16 [M][64] as uint [M][32]
                       const float* __restrict__ dinv,
                       const int* __restrict__ rowstart, const int* __restrict__ esrc,
                       const float* __restrict__ b2, float* __restrict__ out) {
    int node = blockIdx.x * 8 + (threadIdx.x >> 5);
    int l32 = threadIdx.x & 31;
    bool act = l32 < 20;
    float di = dinv[node];
    float acc0 = 0.0f, acc1 = 0.0f;
    if (act) {
        unsigned int u = h2v[(size_t)node * 32 + l32];
        acc0 = di * bflo(u);
        acc1 = di * bfhi(u);
    }
    int e0 = rowstart[node], e1 = rowstart[node + 1];
    int e = e0;
    for (; e + 3 < e1; e += 4) {
        int s0 = esrc[e], s1 = esrc[e + 1], s2 = esrc[e + 2], s3 = esrc[e + 3];
        float w0 = dinv[s0], w1 = dinv[s1], w2 = dinv[s2], w3 = dinv[s3];
        if (act) {
            unsigned int u0 = h2v[(size_t)s0 * 32 + l32];
            unsigned int u1 = h2v[(size_t)s1 * 32 + l32];
            unsigned int u2 = h2v[(size_t)s2 * 32 + l32];
            unsigned int u3 = h2v[(size_t)s3 * 32 + l32];
            acc0 += w0 * bflo(u0) + w1 * bflo(u1) + w2 * bflo(u2) + w3 * bflo(u3);
            acc1 += w0 * bfhi(u0) + w1 * bfhi(u1) + w2 * bfhi(u2) + w3 * bfhi(u3);
        }
    }
    for (; e < e1; ++e) {
        int s = esrc[e];
        float w = dinv[s];
        if (act) {
            unsigned int u = h2v[(size_t)s * 32 + l32];
            acc0 += w * bflo(u);
            acc1 += w * bfhi(u);
        }
    }
    float val0 = -3.0e38f, val1 = -3.0e38f;
    if (act) {
        float2 bb = ((const float2*)b2)[l32];
        val0 = di * acc0 + bb.x;
        val1 = di * acc1 + bb.y;
    }
    float m = fmaxf(val0, val1);
#pragma unroll
    for (int off = 16; off; off >>= 1) m = fmaxf(m, __shfl_xor(m, off));
    float ex = act ? (__expf(val0 - m) + __expf(val1 - m)) : 0.0f;
    float ssum = ex;
#pragma unroll
    for (int off = 16; off; off >>= 1) ssum += __shfl_xor(ssum, off);
    float logs = logf(ssum);
    if (act) {
        float2 o = make_float2(val0 - m - logs, val1 - m - logs);
        ((float2*)(out + (size_t)node * F_OUT))[l32] = o;
    }
}

// ---------------- launch ----------------

extern "C" void kernel_launch(void* const* d_in, const int* in_sizes, int n_in,
                              void* d_out, int out_size, void* d_ws, size_t ws_size,
                              hipStream_t stream) {
    const float* x  = (const float*)d_in[0];
    const int* edge = (const int*)d_in[1];
    const float* W1 = (const float*)d_in[2];
    const float* b1 = (const float*)d_in[3];
    const float* W2 = (const float*)d_in[4];
    const float* b2 = (const float*)d_in[5];
    float* out = (float*)d_out;
    const int* src = edge;
    const int* dst = edge + N_EDGES;

    char* ws = (char*)d_ws;
    size_t off = 0;
    auto alloc = [&](size_t bytes) -> void* {
        void* p = ws + off;
        off = (off + bytes + 255) & ~(size_t)255;
        return p;
    };
    float* dinv   = (float*)alloc((size_t)N_NODES * 4);
    int* cnt      = (int*)alloc((size_t)N_NODES * 4);
    int* slot     = (int*)alloc((size_t)N_EDGES * 4);
    int* rowstart = (int*)alloc((size_t)(N_NODES + 1) * 4);
    int* bsum     = (int*)alloc(128 * 4);
    int* boff     = (int*)alloc(128 * 4);
    int* esrc     = (int*)alloc((size_t)N_EDGES * 4);
    unsigned int* xb       = (unsigned int*)alloc((size_t)N_NODES * F_IN * 2);   // bf16 25.6 MB
    unsigned short* xaggF  = (unsigned short*)alloc((size_t)N_TILES * 8192 * 2); // frag-order, tile-padded
    unsigned short* W1F    = (unsigned short*)alloc((size_t)32768 * 2);
    unsigned short* W2F    = (unsigned short*)alloc((size_t)16384 * 2);
    unsigned short* h2b    = (unsigned short*)alloc((size_t)N_NODES * 64 * 2);   // 12.8 MB
    (void)ws_size; (void)in_sizes; (void)n_in; (void)out_size;

    int nb = (N_NODES + 1023) / 1024;  // 98

    hipMemsetAsync(cnt, 0, (size_t)N_NODES * 4, stream);
    hipLaunchKernelGGL(k_count2, dim3((N_EDGES + 255) / 256), dim3(256), 0, stream, dst, cnt, slot);
    hipLaunchKernelGGL(k_scan_partial, dim3(nb), dim3(256), 0, stream, cnt, rowstart, dinv, bsum);
    hipLaunchKernelGGL(k_scan_blocks, dim3(1), dim3(128), 0, stream, bsum, boff, rowstart, nb);
    hipLaunchKernelGGL(k_add_off, dim3(nb), dim3(256), 0, stream, rowstart, boff);
    hipLaunchKernelGGL(k_fill2, dim3(1024), dim3(256), 0, stream, src, dst, slot, rowstart, esrc);
    hipLaunchKernelGGL(k_cast_x, dim3(N_NODES * F_IN / 4 / 256), dim3(256), 0, stream, x, (uint2*)xb);
    hipLaunchKernelGGL(k_prep_w, dim3(192), dim3(256), 0, stream, W1, W2, W1F, W2F);
    hipLaunchKernelGGL(k_agg1, dim3(N_TILES), dim3(256), 0, stream,
                       (const uint2*)xb, dinv, rowstart, esrc, xaggF);
    hipLaunchKernelGGL(k_fused_gemm, dim3(N_TILES), dim3(256), 0, stream,
                       xaggF, W1F, W2F, b1, h2b);
    hipLaunchKernelGGL(k_agg2, dim3(N_NODES / 8), dim3(256), 0, stream,
                       (const unsigned int*)h2b, dinv, rowstart, esrc, b2, out);
}

// Round 7
// 288.979 us; speedup vs baseline: 2.0555x; 1.0122x over previous
//
#include <hip/hip_runtime.h>

#define N_NODES 100000
#define N_EDGES 1000000
#define F_IN 128
#define F_HID 256
#define F_OUT 40
#define GROUP_NODES 12500  // N_NODES / 8 XCD-partition for the CSR fill
#define N_TILES 1563       // ceil(N_NODES / 64)

typedef __attribute__((ext_vector_type(8))) short bf16x8;
typedef __attribute__((ext_vector_type(4))) float f32x4;

__device__ inline unsigned short f2bf(float f) {
    unsigned int u = __float_as_uint(f);
    return (unsigned short)((u + 0x7fffu + ((u >> 16) & 1u)) >> 16);
}
__device__ inline float bflo(unsigned int u) { return __uint_as_float(u << 16); }
__device__ inline float bfhi(unsigned int u) { return __uint_as_float(u & 0xffff0000u); }
__device__ inline unsigned int pack2(float a, float b) {
    return (unsigned int)f2bf(a) | ((unsigned int)f2bf(b) << 16);
}

// ---------------- CSR build ----------------

__global__ void k_count2(const int* __restrict__ dst, int* __restrict__ cnt,
                         int* __restrict__ slot) {
    int e = blockIdx.x * 256 + threadIdx.x;
    if (e < N_EDGES) slot[e] = atomicAdd(&cnt[dst[e]], 1);
}

__global__ void k_scan_partial(const int* __restrict__ cnt, int* __restrict__ rowstart,
                               float* __restrict__ dinv, int* __restrict__ bsum) {
    __shared__ int wsum[4];
    int tid = threadIdx.x;
    int base = blockIdx.x * 1024 + tid * 4;
    int v[4];
#pragma unroll
    for (int j = 0; j < 4; j++) {
        int i = base + j;
        v[j] = (i < N_NODES) ? cnt[i] : 0;
        if (i < N_NODES) dinv[i] = rsqrtf((float)v[j] + 1.0f);  // +1 self-loop
    }
    int t = v[0] + v[1] + v[2] + v[3];
    int lane = tid & 63, wave = tid >> 6;
    int incl = t;
#pragma unroll
    for (int off = 1; off < 64; off <<= 1) {
        int u = __shfl_up(incl, off);
        if (lane >= off) incl += u;
    }
    if (lane == 63) wsum[wave] = incl;
    __syncthreads();
    int woff = 0;
    for (int w = 0; w < wave; w++) woff += wsum[w];
    int run = woff + incl - t;
#pragma unroll
    for (int j = 0; j < 4; j++) {
        int i = base + j;
        if (i < N_NODES) rowstart[i] = run;
        run += v[j];
    }
    if (tid == 255) bsum[blockIdx.x] = woff + incl;
}

__global__ void k_scan_blocks(const int* __restrict__ bsum, int* __restrict__ boff,
                              int* __restrict__ rowstart, int nb) {
    __shared__ int wtot[2];
    int tid = threadIdx.x;
    int v = (tid < nb) ? bsum[tid] : 0;
    int lane = tid & 63, wave = tid >> 6;
    int incl = v;
#pragma unroll
    for (int off = 1; off < 64; off <<= 1) {
        int u = __shfl_up(incl, off);
        if (lane >= off) incl += u;
    }
    if (lane == 63) wtot[wave] = incl;
    __syncthreads();
    int excl = incl - v + (wave ? wtot[0] : 0);
    if (tid < nb) boff[tid] = excl;
    if (tid == 0) rowstart[N_NODES] = N_EDGES;
}

__global__ void k_add_off(int* __restrict__ rowstart, const int* __restrict__ boff) {
    int base = blockIdx.x * 1024 + threadIdx.x * 4;
    int off = boff[blockIdx.x];
#pragma unroll
    for (int j = 0; j < 4; j++) {
        int i = base + j;
        if (i < N_NODES) rowstart[i] += off;
    }
}

__global__ void k_fill2(const int* __restrict__ src, const int* __restrict__ dst,
                        const int* __restrict__ slot, const int* __restrict__ rowstart,
                        int* __restrict__ esrc) {
    int g = blockIdx.x & 7;
    int bg = blockIdx.x >> 3;
    int nbg = gridDim.x >> 3;
    int lo = g * GROUP_NODES;
    int hi = lo + GROUP_NODES;
    for (int base = (bg * 256 + threadIdx.x) * 4; base < N_EDGES; base += nbg * 1024) {
        int4 d4 = *(const int4*)(dst + base);
#pragma unroll
        for (int j = 0; j < 4; j++) {
            int d = (&d4.x)[j];
            if (d >= lo && d < hi) {
                int s = src[base + j];
                int sl = slot[base + j];
                esrc[rowstart[d] + sl] = s;
            }
        }
    }
}

// ---------------- cast (pre-scaled by dinv) + weight prep, one launch ----------------
// blocks [0, 12800): xs[i] = bf16(dinv[i] * x[i])
// blocks [12800, 12992): W1F/W2F MFMA-fragment-order transform
__global__ void k_cast_prep(const float* __restrict__ x, const float* __restrict__ dinv,
                            uint2* __restrict__ xb,
                            const float* __restrict__ W1, const float* __restrict__ W2,
                            unsigned short* __restrict__ W1F, unsigned short* __restrict__ W2F) {
    if (blockIdx.x < 12800) {
        int i = blockIdx.x * 256 + threadIdx.x;  // one float4 per thread
        float4 v = ((const float4*)x)[i];
        float d = dinv[i >> 5];  // node = i*4/128
        xb[i] = make_uint2(pack2(d * v.x, d * v.y), pack2(d * v.z, d * v.w));
    } else {
        int i = (blockIdx.x - 12800) * 256 + threadIdx.x;  // 49152 total
        if (i < 32768) {
            int j = i & 7, lane = (i >> 3) & 63, mt = (i >> 9) & 7, kc = (i >> 12) & 3, mhalf = i >> 14;
            int l16 = lane & 15, quad = lane >> 4;
            int n = mhalf * 128 + mt * 16 + l16;
            int k = kc * 32 + quad * 8 + j;
            W1F[i] = f2bf(W1[k * F_HID + n]);
        } else {
            int i2 = i - 32768;
            int j = i2 & 7, lane = (i2 >> 3) & 63, mt = (i2 >> 9) & 3, kc = i2 >> 11;
            int l16 = lane & 15, quad = lane >> 4;
            int n = mt * 16 + l16;
            int k = kc * 32 + quad * 8 + j;
            W2F[i2] = (n < F_OUT) ? f2bf(W2[k * F_OUT + n]) : (unsigned short)0;
        }
    }
}

// ---------------- layer 1 aggregation -> fragment-order xaggF ----------------
// xb rows pre-scaled by dinv -> inner loop is a pure gather-sum.
__global__ void k_agg1(const uint2* __restrict__ xb2, const float* __restrict__ dinv,
                       const int* __restrict__ rowstart, const int* __restrict__ esrc,
                       unsigned short* __restrict__ xaggF) {
    int tile = blockIdx.x;
    int group = threadIdx.x >> 5;
    int l32 = threadIdx.x & 31;
    int kc = l32 >> 3;
    int quad = (l32 >> 1) & 3;
    int jb = (l32 & 1) * 4;
    unsigned short* tbase = xaggF + (size_t)tile * 8192;
    for (int it = 0; it < 8; ++it) {
        int row_local = it * 8 + group;
        int node = tile * 64 + row_local;
        if (node >= N_NODES) break;
        uint2 v = xb2[(size_t)node * 32 + l32];
        float a0 = bflo(v.x), a1 = bfhi(v.x);  // self term (xs already dinv-scaled)
        float a2 = bflo(v.y), a3 = bfhi(v.y);
        int e0 = rowstart[node], e1 = rowstart[node + 1];
        int e = e0;
        for (; e + 3 < e1; e += 4) {
            int s0 = esrc[e], s1 = esrc[e + 1], s2 = esrc[e + 2], s3 = esrc[e + 3];
            uint2 u0 = xb2[(size_t)s0 * 32 + l32];
            uint2 u1 = xb2[(size_t)s1 * 32 + l32];
            uint2 u2 = xb2[(size_t)s2 * 32 + l32];
            uint2 u3 = xb2[(size_t)s3 * 32 + l32];
            a0 += bflo(u0.x) + bflo(u1.x) + bflo(u2.x) + bflo(u3.x);
            a1 += bfhi(u0.x) + bfhi(u1.x) + bfhi(u2.x) + bfhi(u3.x);
            a2 += bflo(u0.y) + bflo(u1.y) + bflo(u2.y) + bflo(u3.y);
            a3 += bfhi(u0.y) + bfhi(u1.y) + bfhi(u2.y) + bfhi(u3.y);
        }
        for (; e < e1; ++e) {
            int s = esrc[e];
            uint2 u = xb2[(size_t)s * 32 + l32];
            a0 += bflo(u.x);
            a1 += bfhi(u.x);
            a2 += bflo(u.y);
            a3 += bfhi(u.y);
        }
        float di = dinv[node];
        a0 *= di; a1 *= di; a2 *= di; a3 *= di;
        int nhalf = row_local >> 5, nt = (row_local >> 4) & 1, l16 = row_local & 15;
        size_t off = (size_t)(kc * 4 + nhalf * 2 + nt) * 512 + (quad * 16 + l16) * 8 + jb;
        *(uint2*)(tbase + off) = make_uint2(pack2(a0, a1), pack2(a2, a3));
    }
}

// ---------------- fused GEMM: h2s = bf16( dinv * (relu(xagg@W1+b1) @ W2) ) ----------------
__launch_bounds__(256)
__global__ void k_fused_gemm(const unsigned short* __restrict__ AF,   // xaggF frag-order
                             const unsigned short* __restrict__ W1F,  // frag-order 64 KB
                             const unsigned short* __restrict__ W2F,  // frag-order 32 KB
                             const float* __restrict__ b1,
                             const float* __restrict__ dinv,
                             unsigned short* __restrict__ h2b) {      // bf16 [M][64], dinv-scaled
    __shared__ __align__(16) unsigned short Hs[64][264];  // 33.8 KB
    int tid = threadIdx.x;
    int w = tid >> 6, lane = tid & 63;
    int quad = lane >> 4, l16 = lane & 15;
    int row0 = blockIdx.x * 64;
    int mhalf = w >> 1;
    int nhalf = w & 1;
    const unsigned short* AT = AF + (size_t)blockIdx.x * 8192;

    // ---- stage 1: h[64][256] = relu(xagg @ W1 + b1) -> LDS ----
    f32x4 acc[2][8];
#pragma unroll
    for (int nt = 0; nt < 2; nt++)
#pragma unroll
        for (int mt = 0; mt < 8; mt++) acc[nt][mt] = (f32x4){0.f, 0.f, 0.f, 0.f};

#pragma unroll
    for (int kc = 0; kc < 4; ++kc) {
        bf16x8 bf[2], af[8];
#pragma unroll
        for (int nt = 0; nt < 2; nt++)
            bf[nt] = *(const bf16x8*)(AT + (size_t)(kc * 4 + nhalf * 2 + nt) * 512 + lane * 8);
#pragma unroll
        for (int mt = 0; mt < 8; mt++)
            af[mt] = *(const bf16x8*)(W1F + (size_t)((mhalf * 4 + kc) * 8 + mt) * 512 + lane * 8);
#pragma unroll
        for (int nt = 0; nt < 2; nt++)
#pragma unroll
            for (int mt = 0; mt < 8; mt++)
                acc[nt][mt] = __builtin_amdgcn_mfma_f32_16x16x32_bf16(af[mt], bf[nt], acc[nt][mt], 0, 0, 0);
    }
#pragma unroll
    for (int mt = 0; mt < 8; mt++) {
        int colbase = mhalf * 128 + mt * 16 + quad * 4;
        float4 bb = *(const float4*)(b1 + colbase);
#pragma unroll
        for (int nt = 0; nt < 2; nt++) {
            int nrow = nhalf * 32 + nt * 16 + l16;
            float v0 = fmaxf(acc[nt][mt][0] + bb.x, 0.f);
            float v1 = fmaxf(acc[nt][mt][1] + bb.y, 0.f);
            float v2 = fmaxf(acc[nt][mt][2] + bb.z, 0.f);
            float v3 = fmaxf(acc[nt][mt][3] + bb.w, 0.f);
            *(uint2*)&Hs[nrow][colbase] = make_uint2(pack2(v0, v1), pack2(v2, v3));
        }
    }
    __syncthreads();

    // ---- stage 2: out[64][64] = dinv * (h @ W2) ----
    f32x4 acc2[4];
#pragma unroll
    for (int mt = 0; mt < 4; mt++) acc2[mt] = (f32x4){0.f, 0.f, 0.f, 0.f};
#pragma unroll
    for (int kc = 0; kc < 8; ++kc) {
        int k0 = kc * 32;
        bf16x8 hf = *(const bf16x8*)&Hs[w * 16 + l16][k0 + quad * 8];
        bf16x8 wf[4];
#pragma unroll
        for (int mt = 0; mt < 4; mt++)
            wf[mt] = *(const bf16x8*)(W2F + (size_t)(kc * 4 + mt) * 512 + lane * 8);
#pragma unroll
        for (int mt = 0; mt < 4; mt++)
            acc2[mt] = __builtin_amdgcn_mfma_f32_16x16x32_bf16(wf[mt], hf, acc2[mt], 0, 0, 0);
    }
    int grow = row0 + w * 16 + l16;
    if (grow < N_NODES) {
        float dg = dinv[grow];
#pragma unroll
        for (int mt = 0; mt < 4; mt++) {
            uint2 o = make_uint2(pack2(dg * acc2[mt][0], dg * acc2[mt][1]),
                                 pack2(dg * acc2[mt][2], dg * acc2[mt][3]));
            *(uint2*)(h2b + (size_t)grow * 64 + mt * 16 + quad * 4) = o;
        }
    }
}

// ---------------- layer 2 aggregation + bias + log_softmax ----------------
// h2b rows pre-scaled by dinv -> pure gather-sum, then val = di*acc + b2.
__global__ void k_agg2(const unsigned int* __restrict__ h2v,  // bf16 [M][64] as uint [M][32]
                       const float* __restrict__ dinv,
                       const int* __restrict__ rowstart, const int* __restrict__ esrc,
                       const float* __restrict__ b2, float* __restrict__ out) {
    int node = blockIdx.x * 8 + (threadIdx.x >> 5);
    int l32 = threadIdx.x & 31;
    bool act = l32 < 20;
    float acc0 = 0.0f, acc1 = 0.0f;
    if (act) {
        unsigned int u = h2v[(size_t)node * 32 + l32];  // self term (pre-scaled)
        acc0 = bflo(u);
        acc1 = bfhi(u);
    }
    int e0 = rowstart[node], e1 = rowstart[node + 1];
    int e = e0;
    for (; e + 3 < e1; e += 4) {
        int s0 = esrc[e], s1 = esrc[e + 1], s2 = esrc[e + 2], s3 = esrc[e + 3];
        if (act) {
            unsigned int u0 = h2v[(size_t)s0 * 32 + l32];
            unsigned int u1 = h2v[(size_t)s1 * 32 + l32];
            unsigned int u2 = h2v[(size_t)s2 * 32 + l32];
            unsigned int u3 = h2v[(size_t)s3 * 32 + l32];
            acc0 += bflo(u0) + bflo(u1) + bflo(u2) + bflo(u3);
            acc1 += bfhi(u0) + bfhi(u1) + bfhi(u2) + bfhi(u3);
        }
    }
    for (; e < e1; ++e) {
        int s = esrc[e];
        if (act) {
            unsigned int u = h2v[(size_t)s * 32 + l32];
            acc0 += bflo(u);
            acc1 += bfhi(u);
        }
    }
    float di = dinv[node];
    float val0 = -3.0e38f, val1 = -3.0e38f;
    if (act) {
        float2 bb = ((const float2*)b2)[l32];
        val0 = di * acc0 + bb.x;
        val1 = di * acc1 + bb.y;
    }
    float m = fmaxf(val0, val1);
#pragma unroll
    for (int off = 16; off; off >>= 1) m = fmaxf(m, __shfl_xor(m, off));
    float ex = act ? (__expf(val0 - m) + __expf(val1 - m)) : 0.0f;
    float ssum = ex;
#pragma unroll
    for (int off = 16; off; off >>= 1) ssum += __shfl_xor(ssum, off);
    float logs = logf(ssum);
    if (act) {
        float2 o = make_float2(val0 - m - logs, val1 - m - logs);
        ((float2*)(out + (size_t)node * F_OUT))[l32] = o;
    }
}

// ---------------- launch ----------------

extern "C" void kernel_launch(void* const* d_in, const int* in_sizes, int n_in,
                              void* d_out, int out_size, void* d_ws, size_t ws_size,
                              hipStream_t stream) {
    const float* x  = (const float*)d_in[0];
    const int* edge = (const int*)d_in[1];
    const float* W1 = (const float*)d_in[2];
    const float* b1 = (const float*)d_in[3];
    const float* W2 = (const float*)d_in[4];
    const float* b2 = (const float*)d_in[5];
    float* out = (float*)d_out;
    const int* src = edge;
    const int* dst = edge + N_EDGES;

    char* ws = (char*)d_ws;
    size_t off = 0;
    auto alloc = [&](size_t bytes) -> void* {
        void* p = ws + off;
        off = (off + bytes + 255) & ~(size_t)255;
        return p;
    };
    float* dinv   = (float*)alloc((size_t)N_NODES * 4);
    int* cnt      = (int*)alloc((size_t)N_NODES * 4);
    int* slot     = (int*)alloc((size_t)N_EDGES * 4);
    int* rowstart = (int*)alloc((size_t)(N_NODES + 1) * 4);
    int* bsum     = (int*)alloc(128 * 4);
    int* boff     = (int*)alloc(128 * 4);
    int* esrc     = (int*)alloc((size_t)N_EDGES * 4);
    unsigned int* xb       = (unsigned int*)alloc((size_t)N_NODES * F_IN * 2);   // bf16 25.6 MB
    unsigned short* xaggF  = (unsigned short*)alloc((size_t)N_TILES * 8192 * 2); // frag-order
    unsigned short* W1F    = (unsigned short*)alloc((size_t)32768 * 2);
    unsigned short* W2F    = (unsigned short*)alloc((size_t)16384 * 2);
    unsigned short* h2b    = (unsigned short*)alloc((size_t)N_NODES * 64 * 2);   // 12.8 MB
    (void)ws_size; (void)in_sizes; (void)n_in; (void)out_size;

    int nb = (N_NODES + 1023) / 1024;  // 98

    hipMemsetAsync(cnt, 0, (size_t)N_NODES * 4, stream);
    hipLaunchKernelGGL(k_count2, dim3((N_EDGES + 255) / 256), dim3(256), 0, stream, dst, cnt, slot);
    hipLaunchKernelGGL(k_scan_partial, dim3(nb), dim3(256), 0, stream, cnt, rowstart, dinv, bsum);
    hipLaunchKernelGGL(k_scan_blocks, dim3(1), dim3(128), 0, stream, bsum, boff, rowstart, nb);
    hipLaunchKernelGGL(k_add_off, dim3(nb), dim3(256), 0, stream, rowstart, boff);
    hipLaunchKernelGGL(k_fill2, dim3(1024), dim3(256), 0, stream, src, dst, slot, rowstart, esrc);
    hipLaunchKernelGGL(k_cast_prep, dim3(12992), dim3(256), 0, stream,
                       x, dinv, (uint2*)xb, W1, W2, W1F, W2F);
    hipLaunchKernelGGL(k_agg1, dim3(N_TILES), dim3(256), 0, stream,
                       (const uint2*)xb, dinv, rowstart, esrc, xaggF);
    hipLaunchKernelGGL(k_fused_gemm, dim3(N_TILES), dim3(256), 0, stream,
                       xaggF, W1F, W2F, b1, dinv, h2b);
    hipLaunchKernelGGL(k_agg2, dim3(N_NODES / 8), dim3(256), 0, stream,
                       (const unsigned int*)h2b, dinv, rowstart, esrc, b2, out);
}